// Round 15
// baseline (838.597 us; speedup 1.0000x reference)
//
#include <hip/hip_runtime.h>
#include <hip/hip_bf16.h>
#include <hip/hip_fp16.h>

#define DELTA 2.5749f
#define BN_EPS 1e-5f

#define NBUCK 512   // CSR buckets (node-range partitions)
#define NBLK 256    // partition-pass blocks (256 blocks x 512 thr = full CU coverage)
#define ECAP 3584   // LDS edge staging per bucket (avg ~3125 for E=1.6M)

typedef __attribute__((ext_vector_type(8))) _Float16 f16x8;
typedef __attribute__((ext_vector_type(2))) _Float16 f16x2;
typedef __attribute__((ext_vector_type(4))) float f32x4;

__device__ inline unsigned short f2h(float f) {
    union { _Float16 h; unsigned short u; } v;
    v.h = (_Float16)f;  // RNE
    return v.u;
}

// ---------------------------------------------------------------- CSR build v3: atomic-free radix partition
// Rounds 0-5: device-scope global atomicAdd = memory-side RMW (~40B WRITE each)
// -> zero per-edge global atomics here. Widened to 256 blocks x 512 threads
// (round-13): full CU coverage + 4x waves for latency hiding.

__global__ __launch_bounds__(512) void k_cnt(const int* __restrict__ dst,
                                             int* __restrict__ cnts,
                                             int E, int npb, int CS) {
    __shared__ int hist[NBUCK];
    int t = threadIdx.x;
    hist[t] = 0;
    __syncthreads();
    int s0 = blockIdx.x * CS, s1 = min(s0 + CS, E);
    for (int e = s0 + t; e < s1; e += 512)
        atomicAdd(&hist[dst[e] / npb], 1);
    __syncthreads();
    cnts[blockIdx.x * NBUCK + t] = hist[t];
}

// per-bucket scan over the NBLK block counts -> per-(block,bucket) exclusive
// bases + bucket totals. One block per bucket, NBLK threads.
__global__ void k_bscan1(const int* __restrict__ cnts, int* __restrict__ bases,
                         int* __restrict__ btot) {
    __shared__ int s[NBLK];
    int b = blockIdx.x, t = threadIdx.x;
    int v = cnts[t * NBUCK + b];
    s[t] = v; __syncthreads();
    for (int off = 1; off < NBLK; off <<= 1) {
        int x = (t >= off) ? s[t - off] : 0;
        __syncthreads();
        s[t] += x;
        __syncthreads();
    }
    bases[t * NBUCK + b] = s[t] - v;   // exclusive within bucket
    if (t == NBLK - 1) btot[b] = s[t];
}

// exclusive scan over bucket totals -> bucket bases; also writes rowptr[N]=E.
__global__ void k_btops(const int* __restrict__ btot, int* __restrict__ bbase,
                        int* __restrict__ rowptr, int E, int N) {
    __shared__ int s[NBUCK];
    int t = threadIdx.x;  // 512
    int v = btot[t];
    s[t] = v; __syncthreads();
    for (int off = 1; off < NBUCK; off <<= 1) {
        int x = (t >= off) ? s[t - off] : 0;
        __syncthreads();
        s[t] += x;
        __syncthreads();
    }
    bbase[t] = s[t] - v;
    if (t == 0) rowptr[N] = E;
}

__global__ __launch_bounds__(512) void k_scat(const int* __restrict__ dst,
                                              const int* __restrict__ src,
                                              const int* __restrict__ bases,
                                              const int* __restrict__ bbase,
                                              int2* __restrict__ eDS,
                                              int E, int npb, int CS) {
    __shared__ int cur[NBUCK];
    int t = threadIdx.x;
    cur[t] = bbase[t] + bases[blockIdx.x * NBUCK + t];
    __syncthreads();
    int s0 = blockIdx.x * CS, s1 = min(s0 + CS, E);
    for (int e = s0 + t; e < s1; e += 512) {
        int d = dst[e];
        int p = d / npb;
        int pos = atomicAdd(&cur[p], 1);   // LDS atomic
        eDS[pos] = make_int2(d, src[e]);
    }
}

// one block per bucket: stage edges in LDS, degree-hist, block scan ->
// rowptr slice (global = bucket base + local prefix), LDS-cursor col scatter,
// cnt[] = max(deg,1). Fuses degree/scanx3/fill into one kernel.
__global__ __launch_bounds__(256) void k_csr(const int2* __restrict__ eDS,
                                             const int* __restrict__ bbase,
                                             const int* __restrict__ btot,
                                             int* __restrict__ rowptr,
                                             int* __restrict__ col,
                                             float* __restrict__ cnt,
                                             int npb, int N) {
    __shared__ int2 sE[ECAP];
    __shared__ int pre[256], sc[256];
    int b = blockIdx.x, t = threadIdx.x;
    int lo = b * npb;
    if (lo >= N) return;                    // uniform per block
    int nn = min(npb, N - lo);
    int base = bbase[b], n = btot[b];
    pre[t] = 0;
    __syncthreads();
    const int2* gE = eDS + base;
    for (int i = t; i < n; i += 256) {
        int2 e = gE[i];
        if (i < ECAP) sE[i] = e;
        atomicAdd(&pre[e.x - lo], 1);       // LDS atomic
    }
    __syncthreads();
    int deg = (t < nn) ? pre[t] : 0;
    sc[t] = deg; __syncthreads();
    for (int off = 1; off < 256; off <<= 1) {
        int x = (t >= off) ? sc[t - off] : 0;
        __syncthreads();
        sc[t] += x;
        __syncthreads();
    }
    int excl = sc[t] - deg;
    if (t < nn) {
        rowptr[lo + t] = base + excl;
        cnt[lo + t] = (float)(deg > 0 ? deg : 1);
    }
    __syncthreads();
    pre[t] = excl;                          // reuse as cursors
    __syncthreads();
    for (int i = t; i < n; i += 256) {
        int2 e = (i < ECAP) ? sE[i] : gE[i];
        int pos = atomicAdd(&pre[e.x - lo], 1);  // LDS atomic
        col[base + pos] = e.y;
    }
}

// ---------------------------------------------------------------- weight casts: f32 -> f16, MFMA-fragment-contiguous
__global__ void k_castw_mlp(const float* __restrict__ w, unsigned short* __restrict__ o,
                            int total) {
    int i = blockIdx.x * 256 + threadIdx.x;
    if (i >= total) return;
    int lane = i & 63;
    int tile = (i >> 6) % 12;
    int sc = (i / 768) % 8;
    int layer = i / 6144;
    int r16 = lane & 15, quad = lane >> 4;
    int mat = tile >> 2, nt = tile & 3;
    const float* sp = w + (size_t)(layer * 64 + nt * 16 + r16) * 768
                        + mat * 256 + sc * 32 + quad * 8;
    unsigned short* op = o + (size_t)i * 8;
#pragma unroll
    for (int j = 0; j < 8; j++) op[j] = f2h(sp[j]);
}

// nnW [64 rows][64 k] -> [nt][s][lane][8]
__global__ void k_castw_nn(const float* __restrict__ w, unsigned short* __restrict__ o,
                           int total) {
    int i = blockIdx.x * 256 + threadIdx.x;
    if (i >= total) return;
    int lane = i & 63;
    int s = (i >> 6) & 1;
    int nt = (i >> 7) & 3;
    int layer = i >> 9;
    int r16 = lane & 15, quad = lane >> 4;
    const float* sp = w + (size_t)(layer * 64 + nt * 16 + r16) * 64 + s * 32 + quad * 8;
    unsigned short* op = o + (size_t)i * 8;
#pragma unroll
    for (int j = 0; j < 8; j++) op[j] = f2h(sp[j]);
}

// ---------------------------------------------------------------- fused per-layer agg+MLP (v7b)
// Round-14's fusion raced: phase A gathers read ARBITRARY rows of h while
// finished blocks overwrote their own rows (in/out shared one buffer).
// v7b: ping-pong h buffers -- hIn is read-only for the entire dispatch
// (fully written by the previous dispatch), phase 4 writes hOut. Cross-block
// order is then irrelevant. Fusion wins kept: 5 dispatches deleted, baseF
// L2-hot for phase 0, agg gathers of one block overlap MFMA of co-resident.
#define ACC2(V)                                                            \
    do {                                                                   \
        mx = __builtin_elementwise_max(mx, V);                             \
        float x0 = (float)V[0], x1 = (float)V[1];                          \
        sa += x0; qa = fmaf(x0, x0, qa);                                   \
        sb += x1; qb = fmaf(x1, x1, qb);                                   \
    } while (0)

__global__ __launch_bounds__(256) void k_mlp(const int* __restrict__ rowptr,
                                             const int* __restrict__ col,
                                             unsigned short* __restrict__ baseF,
                                             const float* __restrict__ cnt,
                                             const unsigned short* __restrict__ mW2,
                                             const float* __restrict__ mb,
                                             const unsigned short* __restrict__ hres16,
                                             const float* __restrict__ bnstatPrev,
                                             const float* __restrict__ gammaP,
                                             const float* __restrict__ betaP,
                                             float invN, int first,
                                             const unsigned short* __restrict__ w1F,
                                             const float* __restrict__ b1,
                                             const unsigned short* __restrict__ w2F,
                                             const float* __restrict__ b2,
                                             float* __restrict__ bnstat,
                                             unsigned short* __restrict__ hOut16, int N) {
    __shared__ char smem[36864];
    _Float16* bufA = (_Float16*)smem;             // [128][72] f16
    _Float16* bufB = bufA + 128 * 72;             // [128][72] f16
    _Float16* ldsW = bufB;                        // 12 KB overlay (phase0 only)
    float* red = (float*)bufB;                    // 8 KB overlay (post-barrier)

    int t = threadIdx.x;
    int wave = t >> 6, lane = t & 63;
    int r16 = lane & 15, quad = lane >> 4;
    int n0 = blockIdx.x * 128;
    int m0 = n0 + wave * 32;

    // ---------------- Phase A: aggregate this wave's 32 rows (k_agg body x16)
    {
        int half = lane >> 5;          // which node of the pass pair
        int fl = lane & 31;            // feature-pair index
        int fo2 = fl * 2;
        float scx, scy, shx, shy;
        if (first) {
            scx = 1.f; scy = 1.f; shx = 0.f; shy = 0.f;
        } else {
            float mu0 = bnstatPrev[fo2] * invN, mu1 = bnstatPrev[fo2 + 1] * invN;
            float v0 = bnstatPrev[64 + fo2] * invN - mu0 * mu0;
            float v1 = bnstatPrev[64 + fo2 + 1] * invN - mu1 * mu1;
            scx = rsqrtf(v0 + BN_EPS) * gammaP[fo2];
            scy = rsqrtf(v1 + BN_EPS) * gammaP[fo2 + 1];
            shx = betaP[fo2] - mu0 * scx;
            shy = betaP[fo2 + 1] - mu1 * scy;
        }
        const _Float16* hp = (const _Float16*)hres16;
        const _Float16* hb = hp + fo2;   // per-lane feature base; row = +c*64
#pragma unroll 1
        for (int pass = 0; pass < 16; ++pass) {
            int node = m0 + pass * 2 + half;
            if (node >= N) continue;
            int s0 = rowptr[node], s1 = rowptr[node + 1];
            int deg = s1 - s0;
            float sa = 0.f, sb = 0.f, qa = 0.f, qb = 0.f;
            f16x2 mx;
            mx[0] = (_Float16)(-65504.0f); mx[1] = (_Float16)(-65504.0f);
            int nfull = deg >> 3;
            f16x2 vA[8];
            int cN[8];
            if (nfull >= 1) {
                int cC[8];
                const int* cp = col + s0;
#pragma unroll
                for (int j = 0; j < 8; j++) cC[j] = cp[j];
                if (nfull >= 2) {
#pragma unroll
                    for (int j = 0; j < 8; j++) cN[j] = cp[8 + j];
                }
#pragma unroll
                for (int j = 0; j < 8; j++)
                    vA[j] = *(const f16x2*)(hb + ((size_t)(unsigned)cC[j] << 6));
            }
            for (int b = 1; b < nfull; b++) {
                int cNN[8];
                f16x2 vB[8];
                if (b + 1 < nfull) {
                    const int* cp = col + s0 + (b + 1) * 8;
#pragma unroll
                    for (int j = 0; j < 8; j++) cNN[j] = cp[j];
                }
#pragma unroll
                for (int j = 0; j < 8; j++)
                    vB[j] = *(const f16x2*)(hb + ((size_t)(unsigned)cN[j] << 6));
#pragma unroll
                for (int j = 0; j < 8; j++) ACC2(vA[j]);
#pragma unroll
                for (int j = 0; j < 8; j++) { vA[j] = vB[j]; }
#pragma unroll
                for (int j = 0; j < 8; j++) { cN[j] = cNN[j]; }
            }
            if (nfull >= 1) {
#pragma unroll
                for (int j = 0; j < 8; j++) ACC2(vA[j]);
            }
            int tb = s0 + nfull * 8;
            int rem = s1 - tb;
            if (rem > 0) {
                int cT[8];
                f16x2 vT[8];
#pragma unroll
                for (int j = 0; j < 8; j++) {
                    int idx = (tb + j < s1) ? (tb + j) : (s1 - 1);
                    cT[j] = col[idx];
                }
#pragma unroll
                for (int j = 0; j < 8; j++)
                    vT[j] = *(const f16x2*)(hb + ((size_t)(unsigned)cT[j] << 6));
#pragma unroll
                for (int j = 0; j < 8; j++) {
                    if (j < rem) ACC2(vT[j]);
                }
            }
            float c = (float)(deg > 0 ? deg : 1);
            float ic = 1.f / c;
            float sum0, sum1, max0, max1, mean0, mean1, var0, var1;
            if (deg == 0) {
                sum0 = sum1 = max0 = max1 = mean0 = mean1 = var0 = var1 = 0.f;
            } else {
                sum0 = fmaf(scx, sa, c * shx);
                sum1 = fmaf(scy, sb, c * shy);
                max0 = fmaf(scx, (float)mx[0], shx);
                max1 = fmaf(scy, (float)mx[1], shy);
                float m0f = sa * ic, m1f = sb * ic;
                mean0 = fmaf(scx, m0f, shx);
                mean1 = fmaf(scy, m1f, shy);
                var0 = scx * scx * fmaxf(fmaf(-m0f, m0f, qa * ic), 0.f);
                var1 = scy * scy * fmaxf(fmaf(-m1f, m1f, qb * ic), 0.f);
            }
            size_t bo = (size_t)node * 256 + fo2;
            ushort2 o;
            o.x = f2h(sum0); o.y = f2h(sum1);  *(ushort2*)(baseF + bo) = o;
            o.x = f2h(max0); o.y = f2h(max1);  *(ushort2*)(baseF + bo + 64) = o;
            o.x = f2h(mean0); o.y = f2h(mean1); *(ushort2*)(baseF + bo + 128) = o;
            o.x = f2h(var0); o.y = f2h(var1);  *(ushort2*)(baseF + bo + 192) = o;
        }
    }
    __syncthreads();   // baseF writes drained (vmcnt) -> L2-hot for phase 0

    // ---------------- Phase 0: base[N,256] x 3 matrices, async-staged weights
    const _Float16* aptr0 = (const _Float16*)baseF + (size_t)(m0 + r16) * 256 + quad * 8;
    const _Float16* aptr1 = aptr0 + 16 * 256;
    f32x4 acc0[12], acc1[12];
#pragma unroll
    for (int i = 0; i < 12; i++) {
        acc0[i] = (f32x4){0.f, 0.f, 0.f, 0.f};
        acc1[i] = (f32x4){0.f, 0.f, 0.f, 0.f};
    }
    // prologue: stage chunk 0, load A chunks 0 and 1
    uint4 st0, st1, st2;
    {
        const uint4* sp = (const uint4*)mW2;
        st0 = sp[t]; st1 = sp[t + 256]; st2 = sp[t + 512];
    }
    f16x8 aC0 = *(const f16x8*)(aptr0);
    f16x8 aC1 = *(const f16x8*)(aptr1);
    f16x8 aN0 = *(const f16x8*)(aptr0 + 32);
    f16x8 aN1 = *(const f16x8*)(aptr1 + 32);
    {
        uint4* dp = (uint4*)ldsW;
        dp[t] = st0; dp[t + 256] = st1; dp[t + 512] = st2;
    }
    __syncthreads();

#pragma unroll 1
    for (int sc = 0; sc < 8; sc++) {
        // issue next-chunk weight loads (latency hides under this chunk's MFMAs)
        if (sc < 7) {
            const uint4* sp = (const uint4*)(mW2 + (sc + 1) * 6144);
            st0 = sp[t]; st1 = sp[t + 256]; st2 = sp[t + 512];
        }
        // A prefetch two chunks ahead
        f16x8 aP0, aP1;
        if (sc < 6) {
            aP0 = *(const f16x8*)(aptr0 + (sc + 2) * 32);
            aP1 = *(const f16x8*)(aptr1 + (sc + 2) * 32);
        }
#pragma unroll
        for (int tile = 0; tile < 12; tile++) {
            f16x8 wF = *(const f16x8*)(ldsW + tile * 512 + lane * 8);
            acc0[tile] = __builtin_amdgcn_mfma_f32_16x16x32_f16(aC0, wF, acc0[tile], 0, 0, 0);
            acc1[tile] = __builtin_amdgcn_mfma_f32_16x16x32_f16(aC1, wF, acc1[tile], 0, 0, 0);
        }
        if (sc < 7) {
            __syncthreads();   // all waves done reading chunk sc
            uint4* dp = (uint4*)ldsW;
            dp[t] = st0; dp[t + 256] = st1; dp[t + 512] = st2;
            __syncthreads();   // chunk sc+1 visible
        }
        aC0 = aN0; aC1 = aN1; aN0 = aP0; aN1 = aP1;
    }
    __syncthreads();   // last ldsW reads done before bufB (overlay) is written

    // ---------------- Phase 1a: residual copy into bufA (wave-local rows)
    {
        int nl = wave * 32 + (lane >> 1);
        int fo = (lane & 1) * 32;
        int gn = n0 + nl;
        uint4* dp = (uint4*)(bufA + nl * 72 + fo);
        if (gn < N) {
            const uint4* sp = (const uint4*)(hres16 + (size_t)gn * 64 + fo);
            dp[0] = sp[0]; dp[1] = sp[1]; dp[2] = sp[2]; dp[3] = sp[3];
        } else {
            uint4 z = make_uint4(0, 0, 0, 0);
            dp[0] = z; dp[1] = z; dp[2] = z; dp[3] = z;
        }
    }
    __builtin_amdgcn_wave_barrier();

    // ---------------- Phase 1b: combine accs + bias + scalers + affine residual
    float scf[4], shf[4], mbv[4];
#pragma unroll
    for (int nt = 0; nt < 4; nt++) {
        int f = nt * 16 + r16;
        mbv[nt] = mb[f];
        if (first) {
            scf[nt] = 1.f; shf[nt] = 0.f;
        } else {
            float mu = bnstatPrev[f] * invN;
            float var = bnstatPrev[64 + f] * invN - mu * mu;
            float s = rsqrtf(var + BN_EPS) * gammaP[f];
            scf[nt] = s; shf[nt] = betaP[f] - mu * s;
        }
    }
#pragma unroll
    for (int mt = 0; mt < 2; mt++) {
#pragma unroll
        for (int i = 0; i < 4; i++) {
            int nl = wave * 32 + mt * 16 + quad * 4 + i;
            int gn = n0 + nl;
            if (gn < N) {
                float c = cnt[gn];
                float amp = c / DELTA, att = DELTA / c;
                f32x4* a = mt ? acc1 : acc0;
#pragma unroll
                for (int nt = 0; nt < 4; nt++) {
                    int f = nt * 16 + r16;
                    float r = (float)bufA[nl * 72 + f];
                    float v = a[nt][i] + amp * a[4 + nt][i] + att * a[8 + nt][i]
                            + mbv[nt] + fmaf(r, scf[nt], shf[nt]);
                    bufA[nl * 72 + f] = (_Float16)v;
                }
            }
        }
    }
    __builtin_amdgcn_wave_barrier();

    // ---------------- Phase 2: nn1 (relu(t @ W1 + b1)) -> bufB (wave-local)
    f32x4 accN[8];
#pragma unroll
    for (int i = 0; i < 8; i++) accN[i] = (f32x4){0.f, 0.f, 0.f, 0.f};
#pragma unroll
    for (int s = 0; s < 2; s++) {
        f16x8 fA0 = *(const f16x8*)(bufA + (wave * 32 + r16) * 72 + s * 32 + quad * 8);
        f16x8 fA1 = *(const f16x8*)(bufA + (wave * 32 + 16 + r16) * 72 + s * 32 + quad * 8);
#pragma unroll
        for (int nt = 0; nt < 4; nt++) {
            f16x8 wB = *(const f16x8*)((const _Float16*)w1F + ((nt * 2 + s) * 64 + lane) * 8);
            accN[nt]     = __builtin_amdgcn_mfma_f32_16x16x32_f16(fA0, wB, accN[nt], 0, 0, 0);
            accN[4 + nt] = __builtin_amdgcn_mfma_f32_16x16x32_f16(fA1, wB, accN[4 + nt], 0, 0, 0);
        }
    }
    float b1v[4];
#pragma unroll
    for (int nt = 0; nt < 4; nt++) b1v[nt] = b1[nt * 16 + r16];
#pragma unroll
    for (int mt = 0; mt < 2; mt++) {
#pragma unroll
        for (int i = 0; i < 4; i++) {
            int nl = wave * 32 + mt * 16 + quad * 4 + i;
#pragma unroll
            for (int nt = 0; nt < 4; nt++) {
                float v = fmaxf(accN[mt * 4 + nt][i] + b1v[nt], 0.f);
                bufB[nl * 72 + nt * 16 + r16] = (_Float16)v;
            }
        }
    }
    __builtin_amdgcn_wave_barrier();

    // ---------------- Phase 3: nn2 (relu(u @ W2 + b2)) -> bufA + bnstat partials
    f32x4 accM[8];
#pragma unroll
    for (int i = 0; i < 8; i++) accM[i] = (f32x4){0.f, 0.f, 0.f, 0.f};
#pragma unroll
    for (int s = 0; s < 2; s++) {
        f16x8 fA0 = *(const f16x8*)(bufB + (wave * 32 + r16) * 72 + s * 32 + quad * 8);
        f16x8 fA1 = *(const f16x8*)(bufB + (wave * 32 + 16 + r16) * 72 + s * 32 + quad * 8);
#pragma unroll
        for (int nt = 0; nt < 4; nt++) {
            f16x8 wB = *(const f16x8*)((const _Float16*)w2F + ((nt * 2 + s) * 64 + lane) * 8);
            accM[nt]     = __builtin_amdgcn_mfma_f32_16x16x32_f16(fA0, wB, accM[nt], 0, 0, 0);
            accM[4 + nt] = __builtin_amdgcn_mfma_f32_16x16x32_f16(fA1, wB, accM[4 + nt], 0, 0, 0);
        }
    }
    float b2v[4], s1[4], s2[4];
#pragma unroll
    for (int nt = 0; nt < 4; nt++) {
        b2v[nt] = b2[nt * 16 + r16]; s1[nt] = 0.f; s2[nt] = 0.f;
    }
#pragma unroll
    for (int mt = 0; mt < 2; mt++) {
#pragma unroll
        for (int i = 0; i < 4; i++) {
            int nl = wave * 32 + mt * 16 + quad * 4 + i;
            bool ok = (n0 + nl) < N;
#pragma unroll
            for (int nt = 0; nt < 4; nt++) {
                float v = fmaxf(accM[mt * 4 + nt][i] + b2v[nt], 0.f);
                if (ok) { s1[nt] += v; s2[nt] = fmaf(v, v, s2[nt]); }
                bufA[nl * 72 + nt * 16 + r16] = (_Float16)v;
            }
        }
    }
    __builtin_amdgcn_wave_barrier();

    // ---------------- Phase 4: wave-local coalesced store (to hOut, NOT hres)
    {
        int nl = wave * 32 + (lane >> 1);
        int fo = (lane & 1) * 32;
        int gn = n0 + nl;
        if (gn < N) {
            const uint4* sp = (const uint4*)(bufA + nl * 72 + fo);
            uint4* dp = (uint4*)(hOut16 + (size_t)gn * 64 + fo);
            dp[0] = sp[0]; dp[1] = sp[1]; dp[2] = sp[2]; dp[3] = sp[3];
        }
    }

    // ---------------- bnstat block reduce (red overlays bufB -> barrier first)
    __syncthreads();   // all waves done reading bufB
#pragma unroll
    for (int nt = 0; nt < 4; nt++) {
        int row = wave * 4 + quad;
        red[row * 64 + nt * 16 + r16] = s1[nt];
        red[1024 + row * 64 + nt * 16 + r16] = s2[nt];
    }
    __syncthreads();
    if (t < 128) {
        int d = t & 63, part = t >> 6;
        float tot = 0.f;
#pragma unroll
        for (int r = 0; r < 16; r++) tot += red[part * 1024 + r * 64 + d];
        atomicAdd(&bnstat[part * 64 + d], tot);
    }
}

// ---------------------------------------------------------------- 64x64 GEMM (encoder only)
#define FMA16(ACC0, ACC1, ACC2, ACC3, A, W)                                \
    do {                                                                   \
        ACC0.x = fmaf(A.x, W.x, ACC0.x); ACC0.y = fmaf(A.x, W.y, ACC0.y);  \
        ACC0.z = fmaf(A.x, W.z, ACC0.z); ACC0.w = fmaf(A.x, W.w, ACC0.w);  \
        ACC1.x = fmaf(A.y, W.x, ACC1.x); ACC1.y = fmaf(A.y, W.y, ACC1.y);  \
        ACC1.z = fmaf(A.y, W.z, ACC1.z); ACC1.w = fmaf(A.y, W.w, ACC1.w);  \
        ACC2.x = fmaf(A.z, W.x, ACC2.x); ACC2.y = fmaf(A.z, W.y, ACC2.y);  \
        ACC2.z = fmaf(A.z, W.z, ACC2.z); ACC2.w = fmaf(A.z, W.w, ACC2.w);  \
        ACC3.x = fmaf(A.w, W.x, ACC3.x); ACC3.y = fmaf(A.w, W.y, ACC3.y);  \
        ACC3.z = fmaf(A.w, W.z, ACC3.z); ACC3.w = fmaf(A.w, W.w, ACC3.w);  \
    } while (0)

__global__ __launch_bounds__(256) void k_gemm64(const float* __restrict__ in,
                                                const float* __restrict__ W,
                                                const float* __restrict__ bias,
                                                unsigned short* __restrict__ out16, int N) {
    __shared__ float sInT[64][64];  // [k][node]
    __shared__ float sWT[64][64];   // [k][feat]
    int t = threadIdx.x;
    int tx = t & 15, ty = t >> 4;
    int n0 = blockIdx.x * 64;
    int c4 = tx * 4;
#pragma unroll
    for (int ch = 0; ch < 4; ch++) {
        int row = ch * 16 + ty;
        float4 v = make_float4(0.f, 0.f, 0.f, 0.f);
        if (n0 + row < N) v = *(const float4*)(in + (size_t)(n0 + row) * 64 + c4);
        sInT[c4 + 0][row] = v.x; sInT[c4 + 1][row] = v.y;
        sInT[c4 + 2][row] = v.z; sInT[c4 + 3][row] = v.w;
        float4 w = *(const float4*)(W + (size_t)row * 64 + c4);
        sWT[c4 + 0][row] = w.x; sWT[c4 + 1][row] = w.y;
        sWT[c4 + 2][row] = w.z; sWT[c4 + 3][row] = w.w;
    }
    __syncthreads();
    float4 acc0 = make_float4(0.f, 0.f, 0.f, 0.f);
    float4 acc1 = acc0, acc2 = acc0, acc3 = acc0;
#pragma unroll 8
    for (int k = 0; k < 64; k++) {
        float4 a = *(const float4*)(&sInT[k][ty * 4]);
        float4 w = *(const float4*)(&sWT[k][tx * 4]);
        FMA16(acc0, acc1, acc2, acc3, a, w);
    }
    float4 b4 = *(const float4*)(bias + tx * 4);
#pragma unroll
    for (int i = 0; i < 4; i++) {
        int n = n0 + ty * 4 + i;
        if (n < N) {
            float4 v = (i == 0) ? acc0 : (i == 1) ? acc1 : (i == 2) ? acc2 : acc3;
            v.x += b4.x; v.y += b4.y; v.z += b4.z; v.w += b4.w;
            ushort4 o;
            o.x = f2h(v.x); o.y = f2h(v.y); o.z = f2h(v.z); o.w = f2h(v.w);
            *(ushort4*)(out16 + (size_t)n * 64 + tx * 4) = o;
        }
    }
}

// ---------------------------------------------------------------- pool (batch sorted; BN inline; f16 in)
__global__ void k_pool(const unsigned short* __restrict__ h16, const int* __restrict__ batch,
                       const float* __restrict__ bnstat, const float* __restrict__ gamma,
                       const float* __restrict__ beta, float invN,
                       float* __restrict__ g, int N) {
    int d = threadIdx.x & 63, r = threadIdx.x >> 6;
    float mu = bnstat[d] * invN;
    float var = bnstat[64 + d] * invN - mu * mu;
    float sc = rsqrtf(var + BN_EPS) * gamma[d];
    float sh = beta[d] - mu * sc;
    const _Float16* hp = (const _Float16*)h16;
    int nbase = blockIdx.x * 32;
    float acc = 0.f;
    int gcur = -1;
    for (int i = 0; i < 8; i++) {
        int n = nbase + i * 4 + r;
        if (n < N) {
            int gb = batch[n];
            if (gb != gcur) {
                if (gcur >= 0) atomicAdd(&g[gcur * 64 + d], acc);
                acc = 0.f; gcur = gb;
            }
            acc += fmaf((float)hp[(size_t)n * 64 + d], sc, sh);
        }
    }
    if (gcur >= 0) atomicAdd(&g[gcur * 64 + d], acc);
}

// ---------------------------------------------------------------- head: relu(g@fc1)+fc2
__global__ void k_head(const float* __restrict__ g, const float* __restrict__ fc1W,
                       const float* __restrict__ fc1b, const float* __restrict__ fc2W,
                       const float* __restrict__ fc2b, float* __restrict__ out) {
    __shared__ float sg[64], sg1[64];
    int gi = blockIdx.x, t = threadIdx.x;
    sg[t] = g[gi * 64 + t];
    __syncthreads();
    float a = fc1b[t];
    for (int k = 0; k < 64; k++) a = fmaf(sg[k], fc1W[t * 64 + k], a);
    sg1[t] = fmaxf(a, 0.f);
    __syncthreads();
    if (t < 16) {
        float o = fc2b[t];
        for (int k = 0; k < 64; k++) o = fmaf(sg1[k], fc2W[t * 64 + k], o);
        out[gi * 16 + t] = o;
    }
}

// ---------------------------------------------------------------- launcher
extern "C" void kernel_launch(void* const* d_in, const int* in_sizes, int n_in,
                              void* d_out, int out_size, void* d_ws, size_t ws_size,
                              hipStream_t stream) {
    const float* x       = (const float*)d_in[0];
    const int*   eidx    = (const int*)d_in[1];
    const int*   batch   = (const int*)d_in[2];
    const float* encW    = (const float*)d_in[3];
    const float* encb    = (const float*)d_in[4];
    const float* nnW1    = (const float*)d_in[5];
    const float* nnb1    = (const float*)d_in[6];
    const float* nnW2    = (const float*)d_in[7];
    const float* nnb2    = (const float*)d_in[8];
    const float* mlpW    = (const float*)d_in[9];
    const float* mlpb    = (const float*)d_in[10];
    const float* bnG     = (const float*)d_in[11];
    const float* bnB     = (const float*)d_in[12];
    const float* fc1W    = (const float*)d_in[13];
    const float* fc1b    = (const float*)d_in[14];
    const float* fc2W    = (const float*)d_in[15];
    const float* fc2b    = (const float*)d_in[16];
    float* out = (float*)d_out;

    const int N = in_sizes[0] / 64;
    const int E = in_sizes[1] / 2;
    const int G = 512;
    const int* src = eidx;
    const int* dst = eidx + E;
    const int npb = (N + NBUCK - 1) / NBUCK;   // nodes per bucket (<=256)
    const float invN = 1.f / (float)N;
    const int CS = (E + NBLK - 1) / NBLK;

    // workspace layout
    char* ws = (char*)d_ws;
    size_t off = 0;
    auto alloc = [&](size_t bytes) { size_t r = off; off = (off + bytes + 255) & ~(size_t)255; return r; };
    int*   rowptr  = (int*)(ws + alloc((size_t)(N + 1) * 4));
    int*   col     = (int*)(ws + alloc((size_t)E * 4));
    int2*  eDS     = (int2*)(ws + alloc((size_t)E * 8));
    int*   cnts    = (int*)(ws + alloc((size_t)NBLK * NBUCK * 4));
    int*   bases   = (int*)(ws + alloc((size_t)NBLK * NBUCK * 4));
    int*   btot    = (int*)(ws + alloc(NBUCK * 4));
    int*   bbase   = (int*)(ws + alloc(NBUCK * 4));
    float* cnt     = (float*)(ws + alloc((size_t)N * 4));
    unsigned short* baseF = (unsigned short*)(ws + alloc((size_t)N * 256 * 2 + 131072));  // +pad for OOB tile reads
    unsigned short* hA   = (unsigned short*)(ws + alloc((size_t)N * 64 * 2 + 32768));     // +pad
    unsigned short* hB   = (unsigned short*)(ws + alloc((size_t)N * 64 * 2 + 32768));     // +pad (ping-pong)
    unsigned short* mWF  = (unsigned short*)(ws + alloc((size_t)5 * 64 * 768 * 2));
    unsigned short* nW1F = (unsigned short*)(ws + alloc((size_t)5 * 64 * 64 * 2));
    unsigned short* nW2F = (unsigned short*)(ws + alloc((size_t)5 * 64 * 64 * 2));
    float* bnstats = (float*)(ws + alloc(5 * 128 * 4));
    float* gpool   = (float*)(ws + alloc((size_t)G * 64 * 4));

    hipMemsetAsync(bnstats, 0, 5 * 128 * 4, stream);
    hipMemsetAsync(gpool, 0, (size_t)G * 64 * 4, stream);

    int ngrid64 = (N + 63) / 64;
    int ngrid128 = (N + 127) / 128;

    // CSR build: count -> scans -> scatter -> per-bucket CSR (no global atomics)
    k_cnt<<<NBLK, 512, 0, stream>>>(dst, cnts, E, npb, CS);
    k_bscan1<<<NBUCK, NBLK, 0, stream>>>(cnts, bases, btot);
    k_btops<<<1, NBUCK, 0, stream>>>(btot, bbase, rowptr, E, N);
    k_scat<<<NBLK, 512, 0, stream>>>(dst, src, bases, bbase, eDS, E, npb, CS);
    k_csr<<<NBUCK, 256, 0, stream>>>(eDS, bbase, btot, rowptr, col, cnt, npb, N);

    // cast weights to f16, MFMA-fragment-contiguous ([layer][sc][tile][lane][8])
    k_castw_mlp<<<120, 256, 0, stream>>>(mlpW, mWF, 30720);
    k_castw_nn<<<10, 256, 0, stream>>>(nnW1, nW1F, 2560);
    k_castw_nn<<<10, 256, 0, stream>>>(nnW2, nW2F, 2560);

    // encoder: hA = f16(x @ encW.T + encb)
    k_gemm64<<<ngrid64, 256, 0, stream>>>(x, encW, encb, hA, N);

    for (int i = 0; i < 5; i++) {
        const float* bsPrev = (i == 0) ? bnstats : bnstats + (i - 1) * 128;
        const float* gP = (i == 0) ? bnG : bnG + (i - 1) * 64;
        const float* bP = (i == 0) ? bnB : bnB + (i - 1) * 64;
        int first = (i == 0) ? 1 : 0;
        unsigned short* hIn  = (i & 1) ? hB : hA;
        unsigned short* hOut = (i & 1) ? hA : hB;
        k_mlp<<<ngrid128, 256, 0, stream>>>(rowptr, col, baseF, cnt,
                                            mWF + (size_t)i * 49152, mlpb + i * 64,
                                            hIn, bsPrev, gP, bP, invN, first,
                                            nW1F + (size_t)i * 4096, nnb1 + i * 64,
                                            nW2F + (size_t)i * 4096, nnb2 + i * 64,
                                            bnstats + i * 128, hOut, N);
    }

    // after 5 layers (A->B->A->B->A->B) the final state is in hB
    k_pool<<<(N + 31) / 32, 256, 0, stream>>>(hB, batch, bnstats + 4 * 128,
                                              bnG + 4 * 64, bnB + 4 * 64, invN, gpool, N);
    k_head<<<G, 64, 0, stream>>>(gpool, fc1W, fc1b, fc2W, fc2b, out);
}

// Round 16
// 624.683 us; speedup vs baseline: 1.3424x; 1.3424x over previous
//
#include <hip/hip_runtime.h>
#include <hip/hip_bf16.h>
#include <hip/hip_fp16.h>

#define DELTA 2.5749f
#define BN_EPS 1e-5f

#define NBUCK 512   // CSR buckets (node-range partitions)
#define NBLK 256    // partition-pass blocks (256 blocks x 512 thr = full CU coverage)
#define ECAP 3584   // LDS edge staging per bucket (avg ~3125 for E=1.6M)

typedef __attribute__((ext_vector_type(8))) _Float16 f16x8;
typedef __attribute__((ext_vector_type(2))) _Float16 f16x2;
typedef __attribute__((ext_vector_type(4))) float f32x4;

__device__ inline unsigned short f2h(float f) {
    union { _Float16 h; unsigned short u; } v;
    v.h = (_Float16)f;  // RNE
    return v.u;
}

// ---------------------------------------------------------------- CSR build v3: atomic-free radix partition
// Rounds 0-5: device-scope global atomicAdd = memory-side RMW (~40B WRITE each)
// -> zero per-edge global atomics here. Widened to 256 blocks x 512 threads
// (round-13): full CU coverage + 4x waves for latency hiding.

__global__ __launch_bounds__(512) void k_cnt(const int* __restrict__ dst,
                                             int* __restrict__ cnts,
                                             int E, int npb, int CS) {
    __shared__ int hist[NBUCK];
    int t = threadIdx.x;
    hist[t] = 0;
    __syncthreads();
    int s0 = blockIdx.x * CS, s1 = min(s0 + CS, E);
    for (int e = s0 + t; e < s1; e += 512)
        atomicAdd(&hist[dst[e] / npb], 1);
    __syncthreads();
    cnts[blockIdx.x * NBUCK + t] = hist[t];
}

// per-bucket scan over the NBLK block counts -> per-(block,bucket) exclusive
// bases + bucket totals. One block per bucket, NBLK threads.
__global__ void k_bscan1(const int* __restrict__ cnts, int* __restrict__ bases,
                         int* __restrict__ btot) {
    __shared__ int s[NBLK];
    int b = blockIdx.x, t = threadIdx.x;
    int v = cnts[t * NBUCK + b];
    s[t] = v; __syncthreads();
    for (int off = 1; off < NBLK; off <<= 1) {
        int x = (t >= off) ? s[t - off] : 0;
        __syncthreads();
        s[t] += x;
        __syncthreads();
    }
    bases[t * NBUCK + b] = s[t] - v;   // exclusive within bucket
    if (t == NBLK - 1) btot[b] = s[t];
}

// exclusive scan over bucket totals -> bucket bases; also writes rowptr[N]=E.
__global__ void k_btops(const int* __restrict__ btot, int* __restrict__ bbase,
                        int* __restrict__ rowptr, int E, int N) {
    __shared__ int s[NBUCK];
    int t = threadIdx.x;  // 512
    int v = btot[t];
    s[t] = v; __syncthreads();
    for (int off = 1; off < NBUCK; off <<= 1) {
        int x = (t >= off) ? s[t - off] : 0;
        __syncthreads();
        s[t] += x;
        __syncthreads();
    }
    bbase[t] = s[t] - v;
    if (t == 0) rowptr[N] = E;
}

__global__ __launch_bounds__(512) void k_scat(const int* __restrict__ dst,
                                              const int* __restrict__ src,
                                              const int* __restrict__ bases,
                                              const int* __restrict__ bbase,
                                              int2* __restrict__ eDS,
                                              int E, int npb, int CS) {
    __shared__ int cur[NBUCK];
    int t = threadIdx.x;
    cur[t] = bbase[t] + bases[blockIdx.x * NBUCK + t];
    __syncthreads();
    int s0 = blockIdx.x * CS, s1 = min(s0 + CS, E);
    for (int e = s0 + t; e < s1; e += 512) {
        int d = dst[e];
        int p = d / npb;
        int pos = atomicAdd(&cur[p], 1);   // LDS atomic
        eDS[pos] = make_int2(d, src[e]);
    }
}

// one block per bucket: stage edges in LDS, degree-hist, block scan ->
// rowptr slice (global = bucket base + local prefix), LDS-cursor col scatter,
// cnt[] = max(deg,1). Fuses degree/scanx3/fill into one kernel.
__global__ __launch_bounds__(256) void k_csr(const int2* __restrict__ eDS,
                                             const int* __restrict__ bbase,
                                             const int* __restrict__ btot,
                                             int* __restrict__ rowptr,
                                             int* __restrict__ col,
                                             float* __restrict__ cnt,
                                             int npb, int N) {
    __shared__ int2 sE[ECAP];
    __shared__ int pre[256], sc[256];
    int b = blockIdx.x, t = threadIdx.x;
    int lo = b * npb;
    if (lo >= N) return;                    // uniform per block
    int nn = min(npb, N - lo);
    int base = bbase[b], n = btot[b];
    pre[t] = 0;
    __syncthreads();
    const int2* gE = eDS + base;
    for (int i = t; i < n; i += 256) {
        int2 e = gE[i];
        if (i < ECAP) sE[i] = e;
        atomicAdd(&pre[e.x - lo], 1);       // LDS atomic
    }
    __syncthreads();
    int deg = (t < nn) ? pre[t] : 0;
    sc[t] = deg; __syncthreads();
    for (int off = 1; off < 256; off <<= 1) {
        int x = (t >= off) ? sc[t - off] : 0;
        __syncthreads();
        sc[t] += x;
        __syncthreads();
    }
    int excl = sc[t] - deg;
    if (t < nn) {
        rowptr[lo + t] = base + excl;
        cnt[lo + t] = (float)(deg > 0 ? deg : 1);
    }
    __syncthreads();
    pre[t] = excl;                          // reuse as cursors
    __syncthreads();
    for (int i = t; i < n; i += 256) {
        int2 e = (i < ECAP) ? sE[i] : gE[i];
        int pos = atomicAdd(&pre[e.x - lo], 1);  // LDS atomic
        col[base + pos] = e.y;
    }
}

// ---------------------------------------------------------------- weight casts: f32 -> f16, MFMA-fragment-contiguous
__global__ void k_castw_mlp(const float* __restrict__ w, unsigned short* __restrict__ o,
                            int total) {
    int i = blockIdx.x * 256 + threadIdx.x;
    if (i >= total) return;
    int lane = i & 63;
    int tile = (i >> 6) % 12;
    int sc = (i / 768) % 8;
    int layer = i / 6144;
    int r16 = lane & 15, quad = lane >> 4;
    int mat = tile >> 2, nt = tile & 3;
    const float* sp = w + (size_t)(layer * 64 + nt * 16 + r16) * 768
                        + mat * 256 + sc * 32 + quad * 8;
    unsigned short* op = o + (size_t)i * 8;
#pragma unroll
    for (int j = 0; j < 8; j++) op[j] = f2h(sp[j]);
}

// nnW [64 rows][64 k] -> [nt][s][lane][8]
__global__ void k_castw_nn(const float* __restrict__ w, unsigned short* __restrict__ o,
                           int total) {
    int i = blockIdx.x * 256 + threadIdx.x;
    if (i >= total) return;
    int lane = i & 63;
    int s = (i >> 6) & 1;
    int nt = (i >> 7) & 3;
    int layer = i >> 9;
    int r16 = lane & 15, quad = lane >> 4;
    const float* sp = w + (size_t)(layer * 64 + nt * 16 + r16) * 64 + s * 32 + quad * 8;
    unsigned short* op = o + (size_t)i * 8;
#pragma unroll
    for (int j = 0; j < 8; j++) op[j] = f2h(sp[j]);
}

// ---------------------------------------------------------------- aggregation
// 2 nodes per wave (half-wave each); lane owns an f16x2 feature pair across ALL
// edges of its node -> NO cross-lane reduction. 3-stage software pipeline over
// 8-edge batches. BN affine (from prev layer's bnstat) computed inline.
#define ACC2(V)                                                            \
    do {                                                                   \
        mx = __builtin_elementwise_max(mx, V);                             \
        float x0 = (float)V[0], x1 = (float)V[1];                          \
        sa += x0; qa = fmaf(x0, x0, qa);                                   \
        sb += x1; qb = fmaf(x1, x1, qb);                                   \
    } while (0)

__global__ __launch_bounds__(256) void k_agg(const unsigned short* __restrict__ h16,
                                             const int* __restrict__ rowptr,
                                             const int* __restrict__ col,
                                             const float* __restrict__ bnstat,
                                             const float* __restrict__ gamma,
                                             const float* __restrict__ beta,
                                             float invN, int first,
                                             unsigned short* __restrict__ baseF,
                                             int N) {
    int t = threadIdx.x;
    int lane = t & 63;
    int half = lane >> 5;          // which node of the wave's pair
    int fl = lane & 31;            // feature-pair index (feats fl*2, fl*2+1)
    int node = blockIdx.x * 8 + (t >> 6) * 2 + half;
    if (node >= N) return;
    int fo2 = fl * 2;
    // inline BN affine for this lane's two features
    float scx, scy, shx, shy;
    if (first) {
        scx = 1.f; scy = 1.f; shx = 0.f; shy = 0.f;
    } else {
        float mu0 = bnstat[fo2] * invN, mu1 = bnstat[fo2 + 1] * invN;
        float v0 = bnstat[64 + fo2] * invN - mu0 * mu0;
        float v1 = bnstat[64 + fo2 + 1] * invN - mu1 * mu1;
        scx = rsqrtf(v0 + BN_EPS) * gamma[fo2];
        scy = rsqrtf(v1 + BN_EPS) * gamma[fo2 + 1];
        shx = beta[fo2] - mu0 * scx;
        shy = beta[fo2 + 1] - mu1 * scy;
    }
    const _Float16* hp = (const _Float16*)h16;
    int s0 = rowptr[node], s1 = rowptr[node + 1];
    int deg = s1 - s0;
    float sa = 0.f, sb = 0.f, qa = 0.f, qb = 0.f;
    f16x2 mx;
    mx[0] = (_Float16)(-65504.0f); mx[1] = (_Float16)(-65504.0f);
    const _Float16* hb = hp + fo2;   // per-lane feature base; row = +c*64
    int nfull = deg >> 3;

    f16x2 vA[8];
    int cN[8];
    if (nfull >= 1) {
        int cC[8];
        const int* cp = col + s0;
#pragma unroll
        for (int j = 0; j < 8; j++) cC[j] = cp[j];
        if (nfull >= 2) {
#pragma unroll
            for (int j = 0; j < 8; j++) cN[j] = cp[8 + j];
        }
#pragma unroll
        for (int j = 0; j < 8; j++) vA[j] = *(const f16x2*)(hb + ((size_t)(unsigned)cC[j] << 6));
    }
    for (int b = 1; b < nfull; b++) {
        int cNN[8];
        f16x2 vB[8];
        if (b + 1 < nfull) {
            const int* cp = col + s0 + (b + 1) * 8;
#pragma unroll
            for (int j = 0; j < 8; j++) cNN[j] = cp[j];
        }
#pragma unroll
        for (int j = 0; j < 8; j++) vB[j] = *(const f16x2*)(hb + ((size_t)(unsigned)cN[j] << 6));
#pragma unroll
        for (int j = 0; j < 8; j++) ACC2(vA[j]);
#pragma unroll
        for (int j = 0; j < 8; j++) { vA[j] = vB[j]; }
#pragma unroll
        for (int j = 0; j < 8; j++) { cN[j] = cNN[j]; }
    }
    if (nfull >= 1) {
#pragma unroll
        for (int j = 0; j < 8; j++) ACC2(vA[j]);
    }
    // predicated tail batch (<=7 edges): clamp indices, gather all, mask acc
    int tb = s0 + nfull * 8;
    int rem = s1 - tb;
    if (rem > 0) {
        int cT[8];
        f16x2 vT[8];
#pragma unroll
        for (int j = 0; j < 8; j++) {
            int idx = (tb + j < s1) ? (tb + j) : (s1 - 1);
            cT[j] = col[idx];
        }
#pragma unroll
        for (int j = 0; j < 8; j++) vT[j] = *(const f16x2*)(hb + ((size_t)(unsigned)cT[j] << 6));
#pragma unroll
        for (int j = 0; j < 8; j++) {
            if (j < rem) ACC2(vT[j]);
        }
    }

    float c = (float)(deg > 0 ? deg : 1);
    float ic = 1.f / c;
    float sum0, sum1, max0, max1, mean0, mean1, var0, var1;
    if (deg == 0) {
        sum0 = sum1 = max0 = max1 = mean0 = mean1 = var0 = var1 = 0.f;
    } else {
        // stats of (sc*x + sh): sum' = sc*sum + c*sh; max' = sc*max + sh (sc>0);
        // mean' = sc*mean + sh; var' = sc^2 * relu(sq/c - mean^2)
        sum0 = fmaf(scx, sa, c * shx);
        sum1 = fmaf(scy, sb, c * shy);
        max0 = fmaf(scx, (float)mx[0], shx);
        max1 = fmaf(scy, (float)mx[1], shy);
        float m0 = sa * ic, m1 = sb * ic;
        mean0 = fmaf(scx, m0, shx);
        mean1 = fmaf(scy, m1, shy);
        var0 = scx * scx * fmaxf(fmaf(-m0, m0, qa * ic), 0.f);
        var1 = scy * scy * fmaxf(fmaf(-m1, m1, qb * ic), 0.f);
    }
    size_t b = (size_t)node * 256 + fo2;
    ushort2 o;
    o.x = f2h(sum0); o.y = f2h(sum1);  *(ushort2*)(baseF + b) = o;
    o.x = f2h(max0); o.y = f2h(max1);  *(ushort2*)(baseF + b + 64) = o;
    o.x = f2h(mean0); o.y = f2h(mean1); *(ushort2*)(baseF + b + 128) = o;
    o.x = f2h(var0); o.y = f2h(var1);  *(ushort2*)(baseF + b + 192) = o;
}

// ---------------------------------------------------------------- fused per-layer MLP v5b (round-11/13, 49.9us -- best measured)
// 128 nodes/block, async-staged weights, ldsW/red overlay bufB, wave-local
// phases, default launch bounds. Round-12's 64-node retile regressed (staging
// amortization); round-14/15's agg-fusion regressed (L2 working-set
// contention, FETCH 32->113MB). This split structure is the measured optimum.
__global__ __launch_bounds__(256) void k_mlp(const unsigned short* __restrict__ baseF,
                                             const float* __restrict__ cnt,
                                             const unsigned short* __restrict__ mW2,
                                             const float* __restrict__ mb,
                                             const unsigned short* __restrict__ hres16,
                                             const float* __restrict__ bnstatPrev,
                                             const float* __restrict__ gammaP,
                                             const float* __restrict__ betaP,
                                             float invN, int first,
                                             const unsigned short* __restrict__ w1F,
                                             const float* __restrict__ b1,
                                             const unsigned short* __restrict__ w2F,
                                             const float* __restrict__ b2,
                                             float* __restrict__ bnstat,
                                             unsigned short* __restrict__ hOut16, int N) {
    __shared__ char smem[36864];
    _Float16* bufA = (_Float16*)smem;             // [128][72] f16
    _Float16* bufB = bufA + 128 * 72;             // [128][72] f16
    _Float16* ldsW = bufB;                        // 12 KB overlay (phase0 only)
    float* red = (float*)bufB;                    // 8 KB overlay (post-barrier)

    int t = threadIdx.x;
    int wave = t >> 6, lane = t & 63;
    int r16 = lane & 15, quad = lane >> 4;
    int n0 = blockIdx.x * 128;
    int m0 = n0 + wave * 32;

    // ---------------- Phase 0: base[N,256] x 3 matrices, async-staged weights
    const _Float16* aptr0 = (const _Float16*)baseF + (size_t)(m0 + r16) * 256 + quad * 8;
    const _Float16* aptr1 = aptr0 + 16 * 256;
    f32x4 acc0[12], acc1[12];
#pragma unroll
    for (int i = 0; i < 12; i++) {
        acc0[i] = (f32x4){0.f, 0.f, 0.f, 0.f};
        acc1[i] = (f32x4){0.f, 0.f, 0.f, 0.f};
    }
    // prologue: stage chunk 0, load A chunks 0 and 1
    uint4 st0, st1, st2;
    {
        const uint4* sp = (const uint4*)mW2;
        st0 = sp[t]; st1 = sp[t + 256]; st2 = sp[t + 512];
    }
    f16x8 aC0 = *(const f16x8*)(aptr0);
    f16x8 aC1 = *(const f16x8*)(aptr1);
    f16x8 aN0 = *(const f16x8*)(aptr0 + 32);
    f16x8 aN1 = *(const f16x8*)(aptr1 + 32);
    {
        uint4* dp = (uint4*)ldsW;
        dp[t] = st0; dp[t + 256] = st1; dp[t + 512] = st2;
    }
    __syncthreads();

#pragma unroll 1
    for (int sc = 0; sc < 8; sc++) {
        // issue next-chunk weight loads (latency hides under this chunk's MFMAs)
        if (sc < 7) {
            const uint4* sp = (const uint4*)(mW2 + (sc + 1) * 6144);
            st0 = sp[t]; st1 = sp[t + 256]; st2 = sp[t + 512];
        }
        // A prefetch two chunks ahead
        f16x8 aP0, aP1;
        if (sc < 6) {
            aP0 = *(const f16x8*)(aptr0 + (sc + 2) * 32);
            aP1 = *(const f16x8*)(aptr1 + (sc + 2) * 32);
        }
#pragma unroll
        for (int tile = 0; tile < 12; tile++) {
            f16x8 wF = *(const f16x8*)(ldsW + tile * 512 + lane * 8);
            acc0[tile] = __builtin_amdgcn_mfma_f32_16x16x32_f16(aC0, wF, acc0[tile], 0, 0, 0);
            acc1[tile] = __builtin_amdgcn_mfma_f32_16x16x32_f16(aC1, wF, acc1[tile], 0, 0, 0);
        }
        if (sc < 7) {
            __syncthreads();   // all waves done reading chunk sc
            uint4* dp = (uint4*)ldsW;
            dp[t] = st0; dp[t + 256] = st1; dp[t + 512] = st2;
            __syncthreads();   // chunk sc+1 visible
        }
        aC0 = aN0; aC1 = aN1; aN0 = aP0; aN1 = aP1;
    }
    __syncthreads();   // last ldsW reads done before bufB (overlay) is written

    // ---------------- Phase 1a: residual copy into bufA (wave-local rows)
    {
        int nl = wave * 32 + (lane >> 1);
        int fo = (lane & 1) * 32;
        int gn = n0 + nl;
        uint4* dp = (uint4*)(bufA + nl * 72 + fo);
        if (gn < N) {
            const uint4* sp = (const uint4*)(hres16 + (size_t)gn * 64 + fo);
            dp[0] = sp[0]; dp[1] = sp[1]; dp[2] = sp[2]; dp[3] = sp[3];
        } else {
            uint4 z = make_uint4(0, 0, 0, 0);
            dp[0] = z; dp[1] = z; dp[2] = z; dp[3] = z;
        }
    }
    __builtin_amdgcn_wave_barrier();

    // ---------------- Phase 1b: combine accs + bias + scalers + affine residual
    float scf[4], shf[4], mbv[4];
#pragma unroll
    for (int nt = 0; nt < 4; nt++) {
        int f = nt * 16 + r16;
        mbv[nt] = mb[f];
        if (first) {
            scf[nt] = 1.f; shf[nt] = 0.f;
        } else {
            float mu = bnstatPrev[f] * invN;
            float var = bnstatPrev[64 + f] * invN - mu * mu;
            float s = rsqrtf(var + BN_EPS) * gammaP[f];
            scf[nt] = s; shf[nt] = betaP[f] - mu * s;
        }
    }
#pragma unroll
    for (int mt = 0; mt < 2; mt++) {
#pragma unroll
        for (int i = 0; i < 4; i++) {
            int nl = wave * 32 + mt * 16 + quad * 4 + i;
            int gn = n0 + nl;
            if (gn < N) {
                float c = cnt[gn];
                float amp = c / DELTA, att = DELTA / c;
                f32x4* a = mt ? acc1 : acc0;
#pragma unroll
                for (int nt = 0; nt < 4; nt++) {
                    int f = nt * 16 + r16;
                    float r = (float)bufA[nl * 72 + f];
                    float v = a[nt][i] + amp * a[4 + nt][i] + att * a[8 + nt][i]
                            + mbv[nt] + fmaf(r, scf[nt], shf[nt]);
                    bufA[nl * 72 + f] = (_Float16)v;
                }
            }
        }
    }
    __builtin_amdgcn_wave_barrier();

    // ---------------- Phase 2: nn1 (relu(t @ W1 + b1)) -> bufB (wave-local)
    f32x4 accN[8];
#pragma unroll
    for (int i = 0; i < 8; i++) accN[i] = (f32x4){0.f, 0.f, 0.f, 0.f};
#pragma unroll
    for (int s = 0; s < 2; s++) {
        f16x8 fA0 = *(const f16x8*)(bufA + (wave * 32 + r16) * 72 + s * 32 + quad * 8);
        f16x8 fA1 = *(const f16x8*)(bufA + (wave * 32 + 16 + r16) * 72 + s * 32 + quad * 8);
#pragma unroll
        for (int nt = 0; nt < 4; nt++) {
            f16x8 wB = *(const f16x8*)((const _Float16*)w1F + ((nt * 2 + s) * 64 + lane) * 8);
            accN[nt]     = __builtin_amdgcn_mfma_f32_16x16x32_f16(fA0, wB, accN[nt], 0, 0, 0);
            accN[4 + nt] = __builtin_amdgcn_mfma_f32_16x16x32_f16(fA1, wB, accN[4 + nt], 0, 0, 0);
        }
    }
    float b1v[4];
#pragma unroll
    for (int nt = 0; nt < 4; nt++) b1v[nt] = b1[nt * 16 + r16];
#pragma unroll
    for (int mt = 0; mt < 2; mt++) {
#pragma unroll
        for (int i = 0; i < 4; i++) {
            int nl = wave * 32 + mt * 16 + quad * 4 + i;
#pragma unroll
            for (int nt = 0; nt < 4; nt++) {
                float v = fmaxf(accN[mt * 4 + nt][i] + b1v[nt], 0.f);
                bufB[nl * 72 + nt * 16 + r16] = (_Float16)v;
            }
        }
    }
    __builtin_amdgcn_wave_barrier();

    // ---------------- Phase 3: nn2 (relu(u @ W2 + b2)) -> bufA + bnstat partials
    f32x4 accM[8];
#pragma unroll
    for (int i = 0; i < 8; i++) accM[i] = (f32x4){0.f, 0.f, 0.f, 0.f};
#pragma unroll
    for (int s = 0; s < 2; s++) {
        f16x8 fA0 = *(const f16x8*)(bufB + (wave * 32 + r16) * 72 + s * 32 + quad * 8);
        f16x8 fA1 = *(const f16x8*)(bufB + (wave * 32 + 16 + r16) * 72 + s * 32 + quad * 8);
#pragma unroll
        for (int nt = 0; nt < 4; nt++) {
            f16x8 wB = *(const f16x8*)((const _Float16*)w2F + ((nt * 2 + s) * 64 + lane) * 8);
            accM[nt]     = __builtin_amdgcn_mfma_f32_16x16x32_f16(fA0, wB, accM[nt], 0, 0, 0);
            accM[4 + nt] = __builtin_amdgcn_mfma_f32_16x16x32_f16(fA1, wB, accM[4 + nt], 0, 0, 0);
        }
    }
    float b2v[4], s1[4], s2[4];
#pragma unroll
    for (int nt = 0; nt < 4; nt++) {
        b2v[nt] = b2[nt * 16 + r16]; s1[nt] = 0.f; s2[nt] = 0.f;
    }
#pragma unroll
    for (int mt = 0; mt < 2; mt++) {
#pragma unroll
        for (int i = 0; i < 4; i++) {
            int nl = wave * 32 + mt * 16 + quad * 4 + i;
            bool ok = (n0 + nl) < N;
#pragma unroll
            for (int nt = 0; nt < 4; nt++) {
                float v = fmaxf(accM[mt * 4 + nt][i] + b2v[nt], 0.f);
                if (ok) { s1[nt] += v; s2[nt] = fmaf(v, v, s2[nt]); }
                bufA[nl * 72 + nt * 16 + r16] = (_Float16)v;
            }
        }
    }
    __builtin_amdgcn_wave_barrier();

    // ---------------- Phase 4: wave-local coalesced store
    {
        int nl = wave * 32 + (lane >> 1);
        int fo = (lane & 1) * 32;
        int gn = n0 + nl;
        if (gn < N) {
            const uint4* sp = (const uint4*)(bufA + nl * 72 + fo);
            uint4* dp = (uint4*)(hOut16 + (size_t)gn * 64 + fo);
            dp[0] = sp[0]; dp[1] = sp[1]; dp[2] = sp[2]; dp[3] = sp[3];
        }
    }

    // ---------------- bnstat block reduce (red overlays bufB -> barrier first)
    __syncthreads();   // all waves done reading bufB
#pragma unroll
    for (int nt = 0; nt < 4; nt++) {
        int row = wave * 4 + quad;
        red[row * 64 + nt * 16 + r16] = s1[nt];
        red[1024 + row * 64 + nt * 16 + r16] = s2[nt];
    }
    __syncthreads();
    if (t < 128) {
        int d = t & 63, part = t >> 6;
        float tot = 0.f;
#pragma unroll
        for (int r = 0; r < 16; r++) tot += red[part * 1024 + r * 64 + d];
        atomicAdd(&bnstat[part * 64 + d], tot);
    }
}

// ---------------------------------------------------------------- 64x64 GEMM (encoder only)
#define FMA16(ACC0, ACC1, ACC2, ACC3, A, W)                                \
    do {                                                                   \
        ACC0.x = fmaf(A.x, W.x, ACC0.x); ACC0.y = fmaf(A.x, W.y, ACC0.y);  \
        ACC0.z = fmaf(A.x, W.z, ACC0.z); ACC0.w = fmaf(A.x, W.w, ACC0.w);  \
        ACC1.x = fmaf(A.y, W.x, ACC1.x); ACC1.y = fmaf(A.y, W.y, ACC1.y);  \
        ACC1.z = fmaf(A.y, W.z, ACC1.z); ACC1.w = fmaf(A.y, W.w, ACC1.w);  \
        ACC2.x = fmaf(A.z, W.x, ACC2.x); ACC2.y = fmaf(A.z, W.y, ACC2.y);  \
        ACC2.z = fmaf(A.z, W.z, ACC2.z); ACC2.w = fmaf(A.z, W.w, ACC2.w);  \
        ACC3.x = fmaf(A.w, W.x, ACC3.x); ACC3.y = fmaf(A.w, W.y, ACC3.y);  \
        ACC3.z = fmaf(A.w, W.z, ACC3.z); ACC3.w = fmaf(A.w, W.w, ACC3.w);  \
    } while (0)

__global__ __launch_bounds__(256) void k_gemm64(const float* __restrict__ in,
                                                const float* __restrict__ W,
                                                const float* __restrict__ bias,
                                                unsigned short* __restrict__ out16, int N) {
    __shared__ float sInT[64][64];  // [k][node]
    __shared__ float sWT[64][64];   // [k][feat]
    int t = threadIdx.x;
    int tx = t & 15, ty = t >> 4;
    int n0 = blockIdx.x * 64;
    int c4 = tx * 4;
#pragma unroll
    for (int ch = 0; ch < 4; ch++) {
        int row = ch * 16 + ty;
        float4 v = make_float4(0.f, 0.f, 0.f, 0.f);
        if (n0 + row < N) v = *(const float4*)(in + (size_t)(n0 + row) * 64 + c4);
        sInT[c4 + 0][row] = v.x; sInT[c4 + 1][row] = v.y;
        sInT[c4 + 2][row] = v.z; sInT[c4 + 3][row] = v.w;
        float4 w = *(const float4*)(W + (size_t)row * 64 + c4);
        sWT[c4 + 0][row] = w.x; sWT[c4 + 1][row] = w.y;
        sWT[c4 + 2][row] = w.z; sWT[c4 + 3][row] = w.w;
    }
    __syncthreads();
    float4 acc0 = make_float4(0.f, 0.f, 0.f, 0.f);
    float4 acc1 = acc0, acc2 = acc0, acc3 = acc0;
#pragma unroll 8
    for (int k = 0; k < 64; k++) {
        float4 a = *(const float4*)(&sInT[k][ty * 4]);
        float4 w = *(const float4*)(&sWT[k][tx * 4]);
        FMA16(acc0, acc1, acc2, acc3, a, w);
    }
    float4 b4 = *(const float4*)(bias + tx * 4);
#pragma unroll
    for (int i = 0; i < 4; i++) {
        int n = n0 + ty * 4 + i;
        if (n < N) {
            float4 v = (i == 0) ? acc0 : (i == 1) ? acc1 : (i == 2) ? acc2 : acc3;
            v.x += b4.x; v.y += b4.y; v.z += b4.z; v.w += b4.w;
            ushort4 o;
            o.x = f2h(v.x); o.y = f2h(v.y); o.z = f2h(v.z); o.w = f2h(v.w);
            *(ushort4*)(out16 + (size_t)n * 64 + tx * 4) = o;
        }
    }
}

// ---------------------------------------------------------------- pool (batch sorted; BN inline; f16 in)
__global__ void k_pool(const unsigned short* __restrict__ h16, const int* __restrict__ batch,
                       const float* __restrict__ bnstat, const float* __restrict__ gamma,
                       const float* __restrict__ beta, float invN,
                       float* __restrict__ g, int N) {
    int d = threadIdx.x & 63, r = threadIdx.x >> 6;
    float mu = bnstat[d] * invN;
    float var = bnstat[64 + d] * invN - mu * mu;
    float sc = rsqrtf(var + BN_EPS) * gamma[d];
    float sh = beta[d] - mu * sc;
    const _Float16* hp = (const _Float16*)h16;
    int nbase = blockIdx.x * 32;
    float acc = 0.f;
    int gcur = -1;
    for (int i = 0; i < 8; i++) {
        int n = nbase + i * 4 + r;
        if (n < N) {
            int gb = batch[n];
            if (gb != gcur) {
                if (gcur >= 0) atomicAdd(&g[gcur * 64 + d], acc);
                acc = 0.f; gcur = gb;
            }
            acc += fmaf((float)hp[(size_t)n * 64 + d], sc, sh);
        }
    }
    if (gcur >= 0) atomicAdd(&g[gcur * 64 + d], acc);
}

// ---------------------------------------------------------------- head: relu(g@fc1)+fc2
__global__ void k_head(const float* __restrict__ g, const float* __restrict__ fc1W,
                       const float* __restrict__ fc1b, const float* __restrict__ fc2W,
                       const float* __restrict__ fc2b, float* __restrict__ out) {
    __shared__ float sg[64], sg1[64];
    int gi = blockIdx.x, t = threadIdx.x;
    sg[t] = g[gi * 64 + t];
    __syncthreads();
    float a = fc1b[t];
    for (int k = 0; k < 64; k++) a = fmaf(sg[k], fc1W[t * 64 + k], a);
    sg1[t] = fmaxf(a, 0.f);
    __syncthreads();
    if (t < 16) {
        float o = fc2b[t];
        for (int k = 0; k < 64; k++) o = fmaf(sg1[k], fc2W[t * 64 + k], o);
        out[gi * 16 + t] = o;
    }
}

// ---------------------------------------------------------------- launcher
extern "C" void kernel_launch(void* const* d_in, const int* in_sizes, int n_in,
                              void* d_out, int out_size, void* d_ws, size_t ws_size,
                              hipStream_t stream) {
    const float* x       = (const float*)d_in[0];
    const int*   eidx    = (const int*)d_in[1];
    const int*   batch   = (const int*)d_in[2];
    const float* encW    = (const float*)d_in[3];
    const float* encb    = (const float*)d_in[4];
    const float* nnW1    = (const float*)d_in[5];
    const float* nnb1    = (const float*)d_in[6];
    const float* nnW2    = (const float*)d_in[7];
    const float* nnb2    = (const float*)d_in[8];
    const float* mlpW    = (const float*)d_in[9];
    const float* mlpb    = (const float*)d_in[10];
    const float* bnG     = (const float*)d_in[11];
    const float* bnB     = (const float*)d_in[12];
    const float* fc1W    = (const float*)d_in[13];
    const float* fc1b    = (const float*)d_in[14];
    const float* fc2W    = (const float*)d_in[15];
    const float* fc2b    = (const float*)d_in[16];
    float* out = (float*)d_out;

    const int N = in_sizes[0] / 64;
    const int E = in_sizes[1] / 2;
    const int G = 512;
    const int* src = eidx;
    const int* dst = eidx + E;
    const int npb = (N + NBUCK - 1) / NBUCK;   // nodes per bucket (<=256)
    const float invN = 1.f / (float)N;
    const int CS = (E + NBLK - 1) / NBLK;

    // workspace layout
    char* ws = (char*)d_ws;
    size_t off = 0;
    auto alloc = [&](size_t bytes) { size_t r = off; off = (off + bytes + 255) & ~(size_t)255; return r; };
    int*   rowptr  = (int*)(ws + alloc((size_t)(N + 1) * 4));
    int*   col     = (int*)(ws + alloc((size_t)E * 4));
    int2*  eDS     = (int2*)(ws + alloc((size_t)E * 8));
    int*   cnts    = (int*)(ws + alloc((size_t)NBLK * NBUCK * 4));
    int*   bases   = (int*)(ws + alloc((size_t)NBLK * NBUCK * 4));
    int*   btot    = (int*)(ws + alloc(NBUCK * 4));
    int*   bbase   = (int*)(ws + alloc(NBUCK * 4));
    float* cnt     = (float*)(ws + alloc((size_t)N * 4));
    unsigned short* baseF = (unsigned short*)(ws + alloc((size_t)N * 256 * 2 + 131072));  // +pad for OOB tile reads
    unsigned short* hC16 = (unsigned short*)(ws + alloc((size_t)N * 64 * 2 + 32768));     // +pad
    unsigned short* mWF  = (unsigned short*)(ws + alloc((size_t)5 * 64 * 768 * 2));
    unsigned short* nW1F = (unsigned short*)(ws + alloc((size_t)5 * 64 * 64 * 2));
    unsigned short* nW2F = (unsigned short*)(ws + alloc((size_t)5 * 64 * 64 * 2));
    float* bnstats = (float*)(ws + alloc(5 * 128 * 4));
    float* gpool   = (float*)(ws + alloc((size_t)G * 64 * 4));

    hipMemsetAsync(bnstats, 0, 5 * 128 * 4, stream);
    hipMemsetAsync(gpool, 0, (size_t)G * 64 * 4, stream);

    int ngrid64 = (N + 63) / 64;
    int ngrid128 = (N + 127) / 128;

    // CSR build: count -> scans -> scatter -> per-bucket CSR (no global atomics)
    k_cnt<<<NBLK, 512, 0, stream>>>(dst, cnts, E, npb, CS);
    k_bscan1<<<NBUCK, NBLK, 0, stream>>>(cnts, bases, btot);
    k_btops<<<1, NBUCK, 0, stream>>>(btot, bbase, rowptr, E, N);
    k_scat<<<NBLK, 512, 0, stream>>>(dst, src, bases, bbase, eDS, E, npb, CS);
    k_csr<<<NBUCK, 256, 0, stream>>>(eDS, bbase, btot, rowptr, col, cnt, npb, N);

    // cast weights to f16, MFMA-fragment-contiguous ([layer][sc][tile][lane][8])
    k_castw_mlp<<<120, 256, 0, stream>>>(mlpW, mWF, 30720);
    k_castw_nn<<<10, 256, 0, stream>>>(nnW1, nW1F, 2560);
    k_castw_nn<<<10, 256, 0, stream>>>(nnW2, nW2F, 2560);

    // encoder: hC16 = f16(x @ encW.T + encb)
    k_gemm64<<<ngrid64, 256, 0, stream>>>(x, encW, encb, hC16, N);

    for (int i = 0; i < 5; i++) {
        const float* bsPrev = (i == 0) ? bnstats : bnstats + (i - 1) * 128;
        const float* gP = (i == 0) ? bnG : bnG + (i - 1) * 64;
        const float* bP = (i == 0) ? bnB : bnB + (i - 1) * 64;
        int first = (i == 0) ? 1 : 0;
        k_agg<<<(N + 7) / 8, 256, 0, stream>>>(hC16, rowptr, col, bsPrev, gP, bP,
                                               invN, first, baseF, N);
        k_mlp<<<ngrid128, 256, 0, stream>>>(baseF, cnt,
                                            mWF + (size_t)i * 49152, mlpb + i * 64,
                                            hC16, bsPrev, gP, bP, invN, first,
                                            nW1F + (size_t)i * 4096, nnb1 + i * 64,
                                            nW2F + (size_t)i * 4096, nnb2 + i * 64,
                                            bnstats + i * 128, hC16, N);
    }

    k_pool<<<(N + 31) / 32, 256, 0, stream>>>(hC16, batch, bnstats + 4 * 128,
                                              bnG + 4 * 64, bnB + 4 * 64, invN, gpool, N);
    k_head<<<G, 64, 0, stream>>>(gpool, fc1W, fc1b, fc2W, fc2b, out);
}

// Round 17
// 619.005 us; speedup vs baseline: 1.3548x; 1.0092x over previous
//
#include <hip/hip_runtime.h>
#include <hip/hip_bf16.h>
#include <hip/hip_fp16.h>

#define DELTA 2.5749f
#define BN_EPS 1e-5f

#define NBUCK 512   // CSR buckets (node-range partitions)
#define NBLK 256    // partition-pass blocks (256 blocks x 512 thr = full CU coverage)
#define ECAP 3584   // LDS edge staging per bucket (avg ~3125 for E=1.6M)

typedef __attribute__((ext_vector_type(8))) _Float16 f16x8;
typedef __attribute__((ext_vector_type(2))) _Float16 f16x2;
typedef __attribute__((ext_vector_type(4))) float f32x4;

__device__ inline unsigned short f2h(float f) {
    union { _Float16 h; unsigned short u; } v;
    v.h = (_Float16)f;  // RNE
    return v.u;
}

// ---------------------------------------------------------------- CSR build v3: atomic-free radix partition
// Rounds 0-5: device-scope global atomicAdd = memory-side RMW (~40B WRITE each)
// -> zero per-edge global atomics here. 256 blocks x 512 threads (round-13).
// Round-17: int4 edge loads in k_cnt/k_scat -- dense loops (no predication
// waste, unlike round-3's masked variant), 4 edges/iter quarters the
// load->div->LDS-atomic issue chain.

__global__ __launch_bounds__(512) void k_cnt(const int* __restrict__ dst,
                                             int* __restrict__ cnts,
                                             int E, int npb, int CS) {
    __shared__ int hist[NBUCK];
    int t = threadIdx.x;
    hist[t] = 0;
    __syncthreads();
    int s0 = blockIdx.x * CS, s1 = min(s0 + CS, E);
    for (int e = s0 + t * 4; e < s1; e += 512 * 4) {
        if (e + 3 < s1) {
            int4 d4 = *(const int4*)(dst + e);
            atomicAdd(&hist[d4.x / npb], 1);
            atomicAdd(&hist[d4.y / npb], 1);
            atomicAdd(&hist[d4.z / npb], 1);
            atomicAdd(&hist[d4.w / npb], 1);
        } else {
            for (int k = e; k < s1; k++) atomicAdd(&hist[dst[k] / npb], 1);
        }
    }
    __syncthreads();
    cnts[blockIdx.x * NBUCK + t] = hist[t];
}

// per-bucket scan over the NBLK block counts -> per-(block,bucket) exclusive
// bases + bucket totals. One block per bucket, NBLK threads.
__global__ void k_bscan1(const int* __restrict__ cnts, int* __restrict__ bases,
                         int* __restrict__ btot) {
    __shared__ int s[NBLK];
    int b = blockIdx.x, t = threadIdx.x;
    int v = cnts[t * NBUCK + b];
    s[t] = v; __syncthreads();
    for (int off = 1; off < NBLK; off <<= 1) {
        int x = (t >= off) ? s[t - off] : 0;
        __syncthreads();
        s[t] += x;
        __syncthreads();
    }
    bases[t * NBUCK + b] = s[t] - v;   // exclusive within bucket
    if (t == NBLK - 1) btot[b] = s[t];
}

// exclusive scan over bucket totals -> bucket bases; also writes rowptr[N]=E.
__global__ void k_btops(const int* __restrict__ btot, int* __restrict__ bbase,
                        int* __restrict__ rowptr, int E, int N) {
    __shared__ int s[NBUCK];
    int t = threadIdx.x;  // 512
    int v = btot[t];
    s[t] = v; __syncthreads();
    for (int off = 1; off < NBUCK; off <<= 1) {
        int x = (t >= off) ? s[t - off] : 0;
        __syncthreads();
        s[t] += x;
        __syncthreads();
    }
    bbase[t] = s[t] - v;
    if (t == 0) rowptr[N] = E;
}

__global__ __launch_bounds__(512) void k_scat(const int* __restrict__ dst,
                                              const int* __restrict__ src,
                                              const int* __restrict__ bases,
                                              const int* __restrict__ bbase,
                                              int2* __restrict__ eDS,
                                              int E, int npb, int CS) {
    __shared__ int cur[NBUCK];
    int t = threadIdx.x;
    cur[t] = bbase[t] + bases[blockIdx.x * NBUCK + t];
    __syncthreads();
    int s0 = blockIdx.x * CS, s1 = min(s0 + CS, E);
    for (int e = s0 + t * 4; e < s1; e += 512 * 4) {
        if (e + 3 < s1) {
            int4 d4 = *(const int4*)(dst + e);
            int4 r4 = *(const int4*)(src + e);
            int p0 = atomicAdd(&cur[d4.x / npb], 1);
            int p1 = atomicAdd(&cur[d4.y / npb], 1);
            int p2 = atomicAdd(&cur[d4.z / npb], 1);
            int p3 = atomicAdd(&cur[d4.w / npb], 1);
            eDS[p0] = make_int2(d4.x, r4.x);
            eDS[p1] = make_int2(d4.y, r4.y);
            eDS[p2] = make_int2(d4.z, r4.z);
            eDS[p3] = make_int2(d4.w, r4.w);
        } else {
            for (int k = e; k < s1; k++) {
                int d = dst[k];
                int pos = atomicAdd(&cur[d / npb], 1);
                eDS[pos] = make_int2(d, src[k]);
            }
        }
    }
}

// one block per bucket: stage edges in LDS, degree-hist, block scan ->
// rowptr slice (global = bucket base + local prefix), LDS-cursor col scatter,
// cnt[] = max(deg,1). Fuses degree/scanx3/fill into one kernel.
__global__ __launch_bounds__(256) void k_csr(const int2* __restrict__ eDS,
                                             const int* __restrict__ bbase,
                                             const int* __restrict__ btot,
                                             int* __restrict__ rowptr,
                                             int* __restrict__ col,
                                             float* __restrict__ cnt,
                                             int npb, int N) {
    __shared__ int2 sE[ECAP];
    __shared__ int pre[256], sc[256];
    int b = blockIdx.x, t = threadIdx.x;
    int lo = b * npb;
    if (lo >= N) return;                    // uniform per block
    int nn = min(npb, N - lo);
    int base = bbase[b], n = btot[b];
    pre[t] = 0;
    __syncthreads();
    const int2* gE = eDS + base;
    for (int i = t; i < n; i += 256) {
        int2 e = gE[i];
        if (i < ECAP) sE[i] = e;
        atomicAdd(&pre[e.x - lo], 1);       // LDS atomic
    }
    __syncthreads();
    int deg = (t < nn) ? pre[t] : 0;
    sc[t] = deg; __syncthreads();
    for (int off = 1; off < 256; off <<= 1) {
        int x = (t >= off) ? sc[t - off] : 0;
        __syncthreads();
        sc[t] += x;
        __syncthreads();
    }
    int excl = sc[t] - deg;
    if (t < nn) {
        rowptr[lo + t] = base + excl;
        cnt[lo + t] = (float)(deg > 0 ? deg : 1);
    }
    __syncthreads();
    pre[t] = excl;                          // reuse as cursors
    __syncthreads();
    for (int i = t; i < n; i += 256) {
        int2 e = (i < ECAP) ? sE[i] : gE[i];
        int pos = atomicAdd(&pre[e.x - lo], 1);  // LDS atomic
        col[base + pos] = e.y;
    }
}

// ---------------------------------------------------------------- weight casts: f32 -> f16, MFMA-fragment-contiguous
__global__ void k_castw_mlp(const float* __restrict__ w, unsigned short* __restrict__ o,
                            int total) {
    int i = blockIdx.x * 256 + threadIdx.x;
    if (i >= total) return;
    int lane = i & 63;
    int tile = (i >> 6) % 12;
    int sc = (i / 768) % 8;
    int layer = i / 6144;
    int r16 = lane & 15, quad = lane >> 4;
    int mat = tile >> 2, nt = tile & 3;
    const float* sp = w + (size_t)(layer * 64 + nt * 16 + r16) * 768
                        + mat * 256 + sc * 32 + quad * 8;
    unsigned short* op = o + (size_t)i * 8;
#pragma unroll
    for (int j = 0; j < 8; j++) op[j] = f2h(sp[j]);
}

// nnW [64 rows][64 k] -> [nt][s][lane][8]
__global__ void k_castw_nn(const float* __restrict__ w, unsigned short* __restrict__ o,
                           int total) {
    int i = blockIdx.x * 256 + threadIdx.x;
    if (i >= total) return;
    int lane = i & 63;
    int s = (i >> 6) & 1;
    int nt = (i >> 7) & 3;
    int layer = i >> 9;
    int r16 = lane & 15, quad = lane >> 4;
    const float* sp = w + (size_t)(layer * 64 + nt * 16 + r16) * 64 + s * 32 + quad * 8;
    unsigned short* op = o + (size_t)i * 8;
#pragma unroll
    for (int j = 0; j < 8; j++) op[j] = f2h(sp[j]);
}

// ---------------------------------------------------------------- aggregation
// 2 nodes per wave (half-wave each); lane owns an f16x2 feature pair across ALL
// edges of its node -> NO cross-lane reduction. 3-stage software pipeline over
// 8-edge batches. BN affine (from prev layer's bnstat) computed inline.
#define ACC2(V)                                                            \
    do {                                                                   \
        mx = __builtin_elementwise_max(mx, V);                             \
        float x0 = (float)V[0], x1 = (float)V[1];                          \
        sa += x0; qa = fmaf(x0, x0, qa);                                   \
        sb += x1; qb = fmaf(x1, x1, qb);                                   \
    } while (0)

__global__ __launch_bounds__(256) void k_agg(const unsigned short* __restrict__ h16,
                                             const int* __restrict__ rowptr,
                                             const int* __restrict__ col,
                                             const float* __restrict__ bnstat,
                                             const float* __restrict__ gamma,
                                             const float* __restrict__ beta,
                                             float invN, int first,
                                             unsigned short* __restrict__ baseF,
                                             int N) {
    int t = threadIdx.x;
    int lane = t & 63;
    int half = lane >> 5;          // which node of the wave's pair
    int fl = lane & 31;            // feature-pair index (feats fl*2, fl*2+1)
    int node = blockIdx.x * 8 + (t >> 6) * 2 + half;
    if (node >= N) return;
    int fo2 = fl * 2;
    // inline BN affine for this lane's two features
    float scx, scy, shx, shy;
    if (first) {
        scx = 1.f; scy = 1.f; shx = 0.f; shy = 0.f;
    } else {
        float mu0 = bnstat[fo2] * invN, mu1 = bnstat[fo2 + 1] * invN;
        float v0 = bnstat[64 + fo2] * invN - mu0 * mu0;
        float v1 = bnstat[64 + fo2 + 1] * invN - mu1 * mu1;
        scx = rsqrtf(v0 + BN_EPS) * gamma[fo2];
        scy = rsqrtf(v1 + BN_EPS) * gamma[fo2 + 1];
        shx = beta[fo2] - mu0 * scx;
        shy = beta[fo2 + 1] - mu1 * scy;
    }
    const _Float16* hp = (const _Float16*)h16;
    int s0 = rowptr[node], s1 = rowptr[node + 1];
    int deg = s1 - s0;
    float sa = 0.f, sb = 0.f, qa = 0.f, qb = 0.f;
    f16x2 mx;
    mx[0] = (_Float16)(-65504.0f); mx[1] = (_Float16)(-65504.0f);
    const _Float16* hb = hp + fo2;   // per-lane feature base; row = +c*64
    int nfull = deg >> 3;

    f16x2 vA[8];
    int cN[8];
    if (nfull >= 1) {
        int cC[8];
        const int* cp = col + s0;
#pragma unroll
        for (int j = 0; j < 8; j++) cC[j] = cp[j];
        if (nfull >= 2) {
#pragma unroll
            for (int j = 0; j < 8; j++) cN[j] = cp[8 + j];
        }
#pragma unroll
        for (int j = 0; j < 8; j++) vA[j] = *(const f16x2*)(hb + ((size_t)(unsigned)cC[j] << 6));
    }
    for (int b = 1; b < nfull; b++) {
        int cNN[8];
        f16x2 vB[8];
        if (b + 1 < nfull) {
            const int* cp = col + s0 + (b + 1) * 8;
#pragma unroll
            for (int j = 0; j < 8; j++) cNN[j] = cp[j];
        }
#pragma unroll
        for (int j = 0; j < 8; j++) vB[j] = *(const f16x2*)(hb + ((size_t)(unsigned)cN[j] << 6));
#pragma unroll
        for (int j = 0; j < 8; j++) ACC2(vA[j]);
#pragma unroll
        for (int j = 0; j < 8; j++) { vA[j] = vB[j]; }
#pragma unroll
        for (int j = 0; j < 8; j++) { cN[j] = cNN[j]; }
    }
    if (nfull >= 1) {
#pragma unroll
        for (int j = 0; j < 8; j++) ACC2(vA[j]);
    }
    // predicated tail batch (<=7 edges): clamp indices, gather all, mask acc
    int tb = s0 + nfull * 8;
    int rem = s1 - tb;
    if (rem > 0) {
        int cT[8];
        f16x2 vT[8];
#pragma unroll
        for (int j = 0; j < 8; j++) {
            int idx = (tb + j < s1) ? (tb + j) : (s1 - 1);
            cT[j] = col[idx];
        }
#pragma unroll
        for (int j = 0; j < 8; j++) vT[j] = *(const f16x2*)(hb + ((size_t)(unsigned)cT[j] << 6));
#pragma unroll
        for (int j = 0; j < 8; j++) {
            if (j < rem) ACC2(vT[j]);
        }
    }

    float c = (float)(deg > 0 ? deg : 1);
    float ic = 1.f / c;
    float sum0, sum1, max0, max1, mean0, mean1, var0, var1;
    if (deg == 0) {
        sum0 = sum1 = max0 = max1 = mean0 = mean1 = var0 = var1 = 0.f;
    } else {
        // stats of (sc*x + sh): sum' = sc*sum + c*sh; max' = sc*max + sh (sc>0);
        // mean' = sc*mean + sh; var' = sc^2 * relu(sq/c - mean^2)
        sum0 = fmaf(scx, sa, c * shx);
        sum1 = fmaf(scy, sb, c * shy);
        max0 = fmaf(scx, (float)mx[0], shx);
        max1 = fmaf(scy, (float)mx[1], shy);
        float m0 = sa * ic, m1 = sb * ic;
        mean0 = fmaf(scx, m0, shx);
        mean1 = fmaf(scy, m1, shy);
        var0 = scx * scx * fmaxf(fmaf(-m0, m0, qa * ic), 0.f);
        var1 = scy * scy * fmaxf(fmaf(-m1, m1, qb * ic), 0.f);
    }
    size_t b = (size_t)node * 256 + fo2;
    ushort2 o;
    o.x = f2h(sum0); o.y = f2h(sum1);  *(ushort2*)(baseF + b) = o;
    o.x = f2h(max0); o.y = f2h(max1);  *(ushort2*)(baseF + b + 64) = o;
    o.x = f2h(mean0); o.y = f2h(mean1); *(ushort2*)(baseF + b + 128) = o;
    o.x = f2h(var0); o.y = f2h(var1);  *(ushort2*)(baseF + b + 192) = o;
}

// ---------------------------------------------------------------- fused per-layer MLP v5b (round-11/13, best measured)
// 128 nodes/block, async-staged weights, ldsW/red overlay bufB, wave-local
// phases, default launch bounds. Round-12's 64-node retile regressed (staging
// amortization); round-14/15's agg-fusion regressed (L2 working-set
// contention, FETCH 32->113MB). This split structure is the measured optimum.
__global__ __launch_bounds__(256) void k_mlp(const unsigned short* __restrict__ baseF,
                                             const float* __restrict__ cnt,
                                             const unsigned short* __restrict__ mW2,
                                             const float* __restrict__ mb,
                                             const unsigned short* __restrict__ hres16,
                                             const float* __restrict__ bnstatPrev,
                                             const float* __restrict__ gammaP,
                                             const float* __restrict__ betaP,
                                             float invN, int first,
                                             const unsigned short* __restrict__ w1F,
                                             const float* __restrict__ b1,
                                             const unsigned short* __restrict__ w2F,
                                             const float* __restrict__ b2,
                                             float* __restrict__ bnstat,
                                             unsigned short* __restrict__ hOut16, int N) {
    __shared__ char smem[36864];
    _Float16* bufA = (_Float16*)smem;             // [128][72] f16
    _Float16* bufB = bufA + 128 * 72;             // [128][72] f16
    _Float16* ldsW = bufB;                        // 12 KB overlay (phase0 only)
    float* red = (float*)bufB;                    // 8 KB overlay (post-barrier)

    int t = threadIdx.x;
    int wave = t >> 6, lane = t & 63;
    int r16 = lane & 15, quad = lane >> 4;
    int n0 = blockIdx.x * 128;
    int m0 = n0 + wave * 32;

    // ---------------- Phase 0: base[N,256] x 3 matrices, async-staged weights
    const _Float16* aptr0 = (const _Float16*)baseF + (size_t)(m0 + r16) * 256 + quad * 8;
    const _Float16* aptr1 = aptr0 + 16 * 256;
    f32x4 acc0[12], acc1[12];
#pragma unroll
    for (int i = 0; i < 12; i++) {
        acc0[i] = (f32x4){0.f, 0.f, 0.f, 0.f};
        acc1[i] = (f32x4){0.f, 0.f, 0.f, 0.f};
    }
    // prologue: stage chunk 0, load A chunks 0 and 1
    uint4 st0, st1, st2;
    {
        const uint4* sp = (const uint4*)mW2;
        st0 = sp[t]; st1 = sp[t + 256]; st2 = sp[t + 512];
    }
    f16x8 aC0 = *(const f16x8*)(aptr0);
    f16x8 aC1 = *(const f16x8*)(aptr1);
    f16x8 aN0 = *(const f16x8*)(aptr0 + 32);
    f16x8 aN1 = *(const f16x8*)(aptr1 + 32);
    {
        uint4* dp = (uint4*)ldsW;
        dp[t] = st0; dp[t + 256] = st1; dp[t + 512] = st2;
    }
    __syncthreads();

#pragma unroll 1
    for (int sc = 0; sc < 8; sc++) {
        // issue next-chunk weight loads (latency hides under this chunk's MFMAs)
        if (sc < 7) {
            const uint4* sp = (const uint4*)(mW2 + (sc + 1) * 6144);
            st0 = sp[t]; st1 = sp[t + 256]; st2 = sp[t + 512];
        }
        // A prefetch two chunks ahead
        f16x8 aP0, aP1;
        if (sc < 6) {
            aP0 = *(const f16x8*)(aptr0 + (sc + 2) * 32);
            aP1 = *(const f16x8*)(aptr1 + (sc + 2) * 32);
        }
#pragma unroll
        for (int tile = 0; tile < 12; tile++) {
            f16x8 wF = *(const f16x8*)(ldsW + tile * 512 + lane * 8);
            acc0[tile] = __builtin_amdgcn_mfma_f32_16x16x32_f16(aC0, wF, acc0[tile], 0, 0, 0);
            acc1[tile] = __builtin_amdgcn_mfma_f32_16x16x32_f16(aC1, wF, acc1[tile], 0, 0, 0);
        }
        if (sc < 7) {
            __syncthreads();   // all waves done reading chunk sc
            uint4* dp = (uint4*)ldsW;
            dp[t] = st0; dp[t + 256] = st1; dp[t + 512] = st2;
            __syncthreads();   // chunk sc+1 visible
        }
        aC0 = aN0; aC1 = aN1; aN0 = aP0; aN1 = aP1;
    }
    __syncthreads();   // last ldsW reads done before bufB (overlay) is written

    // ---------------- Phase 1a: residual copy into bufA (wave-local rows)
    {
        int nl = wave * 32 + (lane >> 1);
        int fo = (lane & 1) * 32;
        int gn = n0 + nl;
        uint4* dp = (uint4*)(bufA + nl * 72 + fo);
        if (gn < N) {
            const uint4* sp = (const uint4*)(hres16 + (size_t)gn * 64 + fo);
            dp[0] = sp[0]; dp[1] = sp[1]; dp[2] = sp[2]; dp[3] = sp[3];
        } else {
            uint4 z = make_uint4(0, 0, 0, 0);
            dp[0] = z; dp[1] = z; dp[2] = z; dp[3] = z;
        }
    }
    __builtin_amdgcn_wave_barrier();

    // ---------------- Phase 1b: combine accs + bias + scalers + affine residual
    float scf[4], shf[4], mbv[4];
#pragma unroll
    for (int nt = 0; nt < 4; nt++) {
        int f = nt * 16 + r16;
        mbv[nt] = mb[f];
        if (first) {
            scf[nt] = 1.f; shf[nt] = 0.f;
        } else {
            float mu = bnstatPrev[f] * invN;
            float var = bnstatPrev[64 + f] * invN - mu * mu;
            float s = rsqrtf(var + BN_EPS) * gammaP[f];
            scf[nt] = s; shf[nt] = betaP[f] - mu * s;
        }
    }
#pragma unroll
    for (int mt = 0; mt < 2; mt++) {
#pragma unroll
        for (int i = 0; i < 4; i++) {
            int nl = wave * 32 + mt * 16 + quad * 4 + i;
            int gn = n0 + nl;
            if (gn < N) {
                float c = cnt[gn];
                float amp = c / DELTA, att = DELTA / c;
                f32x4* a = mt ? acc1 : acc0;
#pragma unroll
                for (int nt = 0; nt < 4; nt++) {
                    int f = nt * 16 + r16;
                    float r = (float)bufA[nl * 72 + f];
                    float v = a[nt][i] + amp * a[4 + nt][i] + att * a[8 + nt][i]
                            + mbv[nt] + fmaf(r, scf[nt], shf[nt]);
                    bufA[nl * 72 + f] = (_Float16)v;
                }
            }
        }
    }
    __builtin_amdgcn_wave_barrier();

    // ---------------- Phase 2: nn1 (relu(t @ W1 + b1)) -> bufB (wave-local)
    f32x4 accN[8];
#pragma unroll
    for (int i = 0; i < 8; i++) accN[i] = (f32x4){0.f, 0.f, 0.f, 0.f};
#pragma unroll
    for (int s = 0; s < 2; s++) {
        f16x8 fA0 = *(const f16x8*)(bufA + (wave * 32 + r16) * 72 + s * 32 + quad * 8);
        f16x8 fA1 = *(const f16x8*)(bufA + (wave * 32 + 16 + r16) * 72 + s * 32 + quad * 8);
#pragma unroll
        for (int nt = 0; nt < 4; nt++) {
            f16x8 wB = *(const f16x8*)((const _Float16*)w1F + ((nt * 2 + s) * 64 + lane) * 8);
            accN[nt]     = __builtin_amdgcn_mfma_f32_16x16x32_f16(fA0, wB, accN[nt], 0, 0, 0);
            accN[4 + nt] = __builtin_amdgcn_mfma_f32_16x16x32_f16(fA1, wB, accN[4 + nt], 0, 0, 0);
        }
    }
    float b1v[4];
#pragma unroll
    for (int nt = 0; nt < 4; nt++) b1v[nt] = b1[nt * 16 + r16];
#pragma unroll
    for (int mt = 0; mt < 2; mt++) {
#pragma unroll
        for (int i = 0; i < 4; i++) {
            int nl = wave * 32 + mt * 16 + quad * 4 + i;
#pragma unroll
            for (int nt = 0; nt < 4; nt++) {
                float v = fmaxf(accN[mt * 4 + nt][i] + b1v[nt], 0.f);
                bufB[nl * 72 + nt * 16 + r16] = (_Float16)v;
            }
        }
    }
    __builtin_amdgcn_wave_barrier();

    // ---------------- Phase 3: nn2 (relu(u @ W2 + b2)) -> bufA + bnstat partials
    f32x4 accM[8];
#pragma unroll
    for (int i = 0; i < 8; i++) accM[i] = (f32x4){0.f, 0.f, 0.f, 0.f};
#pragma unroll
    for (int s = 0; s < 2; s++) {
        f16x8 fA0 = *(const f16x8*)(bufB + (wave * 32 + r16) * 72 + s * 32 + quad * 8);
        f16x8 fA1 = *(const f16x8*)(bufB + (wave * 32 + 16 + r16) * 72 + s * 32 + quad * 8);
#pragma unroll
        for (int nt = 0; nt < 4; nt++) {
            f16x8 wB = *(const f16x8*)((const _Float16*)w2F + ((nt * 2 + s) * 64 + lane) * 8);
            accM[nt]     = __builtin_amdgcn_mfma_f32_16x16x32_f16(fA0, wB, accM[nt], 0, 0, 0);
            accM[4 + nt] = __builtin_amdgcn_mfma_f32_16x16x32_f16(fA1, wB, accM[4 + nt], 0, 0, 0);
        }
    }
    float b2v[4], s1[4], s2[4];
#pragma unroll
    for (int nt = 0; nt < 4; nt++) {
        b2v[nt] = b2[nt * 16 + r16]; s1[nt] = 0.f; s2[nt] = 0.f;
    }
#pragma unroll
    for (int mt = 0; mt < 2; mt++) {
#pragma unroll
        for (int i = 0; i < 4; i++) {
            int nl = wave * 32 + mt * 16 + quad * 4 + i;
            bool ok = (n0 + nl) < N;
#pragma unroll
            for (int nt = 0; nt < 4; nt++) {
                float v = fmaxf(accM[mt * 4 + nt][i] + b2v[nt], 0.f);
                if (ok) { s1[nt] += v; s2[nt] = fmaf(v, v, s2[nt]); }
                bufA[nl * 72 + nt * 16 + r16] = (_Float16)v;
            }
        }
    }
    __builtin_amdgcn_wave_barrier();

    // ---------------- Phase 4: wave-local coalesced store
    {
        int nl = wave * 32 + (lane >> 1);
        int fo = (lane & 1) * 32;
        int gn = n0 + nl;
        if (gn < N) {
            const uint4* sp = (const uint4*)(bufA + nl * 72 + fo);
            uint4* dp = (uint4*)(hOut16 + (size_t)gn * 64 + fo);
            dp[0] = sp[0]; dp[1] = sp[1]; dp[2] = sp[2]; dp[3] = sp[3];
        }
    }

    // ---------------- bnstat block reduce (red overlays bufB -> barrier first)
    __syncthreads();   // all waves done reading bufB
#pragma unroll
    for (int nt = 0; nt < 4; nt++) {
        int row = wave * 4 + quad;
        red[row * 64 + nt * 16 + r16] = s1[nt];
        red[1024 + row * 64 + nt * 16 + r16] = s2[nt];
    }
    __syncthreads();
    if (t < 128) {
        int d = t & 63, part = t >> 6;
        float tot = 0.f;
#pragma unroll
        for (int r = 0; r < 16; r++) tot += red[part * 1024 + r * 64 + d];
        atomicAdd(&bnstat[part * 64 + d], tot);
    }
}

// ---------------------------------------------------------------- 64x64 GEMM (encoder only)
#define FMA16(ACC0, ACC1, ACC2, ACC3, A, W)                                \
    do {                                                                   \
        ACC0.x = fmaf(A.x, W.x, ACC0.x); ACC0.y = fmaf(A.x, W.y, ACC0.y);  \
        ACC0.z = fmaf(A.x, W.z, ACC0.z); ACC0.w = fmaf(A.x, W.w, ACC0.w);  \
        ACC1.x = fmaf(A.y, W.x, ACC1.x); ACC1.y = fmaf(A.y, W.y, ACC1.y);  \
        ACC1.z = fmaf(A.y, W.z, ACC1.z); ACC1.w = fmaf(A.y, W.w, ACC1.w);  \
        ACC2.x = fmaf(A.z, W.x, ACC2.x); ACC2.y = fmaf(A.z, W.y, ACC2.y);  \
        ACC2.z = fmaf(A.z, W.z, ACC2.z); ACC2.w = fmaf(A.z, W.w, ACC2.w);  \
        ACC3.x = fmaf(A.w, W.x, ACC3.x); ACC3.y = fmaf(A.w, W.y, ACC3.y);  \
        ACC3.z = fmaf(A.w, W.z, ACC3.z); ACC3.w = fmaf(A.w, W.w, ACC3.w);  \
    } while (0)

__global__ __launch_bounds__(256) void k_gemm64(const float* __restrict__ in,
                                                const float* __restrict__ W,
                                                const float* __restrict__ bias,
                                                unsigned short* __restrict__ out16, int N) {
    __shared__ float sInT[64][64];  // [k][node]
    __shared__ float sWT[64][64];   // [k][feat]
    int t = threadIdx.x;
    int tx = t & 15, ty = t >> 4;
    int n0 = blockIdx.x * 64;
    int c4 = tx * 4;
#pragma unroll
    for (int ch = 0; ch < 4; ch++) {
        int row = ch * 16 + ty;
        float4 v = make_float4(0.f, 0.f, 0.f, 0.f);
        if (n0 + row < N) v = *(const float4*)(in + (size_t)(n0 + row) * 64 + c4);
        sInT[c4 + 0][row] = v.x; sInT[c4 + 1][row] = v.y;
        sInT[c4 + 2][row] = v.z; sInT[c4 + 3][row] = v.w;
        float4 w = *(const float4*)(W + (size_t)row * 64 + c4);
        sWT[c4 + 0][row] = w.x; sWT[c4 + 1][row] = w.y;
        sWT[c4 + 2][row] = w.z; sWT[c4 + 3][row] = w.w;
    }
    __syncthreads();
    float4 acc0 = make_float4(0.f, 0.f, 0.f, 0.f);
    float4 acc1 = acc0, acc2 = acc0, acc3 = acc0;
#pragma unroll 8
    for (int k = 0; k < 64; k++) {
        float4 a = *(const float4*)(&sInT[k][ty * 4]);
        float4 w = *(const float4*)(&sWT[k][tx * 4]);
        FMA16(acc0, acc1, acc2, acc3, a, w);
    }
    float4 b4 = *(const float4*)(bias + tx * 4);
#pragma unroll
    for (int i = 0; i < 4; i++) {
        int n = n0 + ty * 4 + i;
        if (n < N) {
            float4 v = (i == 0) ? acc0 : (i == 1) ? acc1 : (i == 2) ? acc2 : acc3;
            v.x += b4.x; v.y += b4.y; v.z += b4.z; v.w += b4.w;
            ushort4 o;
            o.x = f2h(v.x); o.y = f2h(v.y); o.z = f2h(v.z); o.w = f2h(v.w);
            *(ushort4*)(out16 + (size_t)n * 64 + tx * 4) = o;
        }
    }
}

// ---------------------------------------------------------------- pool (batch sorted; BN inline; f16 in)
__global__ void k_pool(const unsigned short* __restrict__ h16, const int* __restrict__ batch,
                       const float* __restrict__ bnstat, const float* __restrict__ gamma,
                       const float* __restrict__ beta, float invN,
                       float* __restrict__ g, int N) {
    int d = threadIdx.x & 63, r = threadIdx.x >> 6;
    float mu = bnstat[d] * invN;
    float var = bnstat[64 + d] * invN - mu * mu;
    float sc = rsqrtf(var + BN_EPS) * gamma[d];
    float sh = beta[d] - mu * sc;
    const _Float16* hp = (const _Float16*)h16;
    int nbase = blockIdx.x * 32;
    float acc = 0.f;
    int gcur = -1;
    for (int i = 0; i < 8; i++) {
        int n = nbase + i * 4 + r;
        if (n < N) {
            int gb = batch[n];
            if (gb != gcur) {
                if (gcur >= 0) atomicAdd(&g[gcur * 64 + d], acc);
                acc = 0.f; gcur = gb;
            }
            acc += fmaf((float)hp[(size_t)n * 64 + d], sc, sh);
        }
    }
    if (gcur >= 0) atomicAdd(&g[gcur * 64 + d], acc);
}

// ---------------------------------------------------------------- head: relu(g@fc1)+fc2
__global__ void k_head(const float* __restrict__ g, const float* __restrict__ fc1W,
                       const float* __restrict__ fc1b, const float* __restrict__ fc2W,
                       const float* __restrict__ fc2b, float* __restrict__ out) {
    __shared__ float sg[64], sg1[64];
    int gi = blockIdx.x, t = threadIdx.x;
    sg[t] = g[gi * 64 + t];
    __syncthreads();
    float a = fc1b[t];
    for (int k = 0; k < 64; k++) a = fmaf(sg[k], fc1W[t * 64 + k], a);
    sg1[t] = fmaxf(a, 0.f);
    __syncthreads();
    if (t < 16) {
        float o = fc2b[t];
        for (int k = 0; k < 64; k++) o = fmaf(sg1[k], fc2W[t * 64 + k], o);
        out[gi * 16 + t] = o;
    }
}

// ---------------------------------------------------------------- launcher
extern "C" void kernel_launch(void* const* d_in, const int* in_sizes, int n_in,
                              void* d_out, int out_size, void* d_ws, size_t ws_size,
                              hipStream_t stream) {
    const float* x       = (const float*)d_in[0];
    const int*   eidx    = (const int*)d_in[1];
    const int*   batch   = (const int*)d_in[2];
    const float* encW    = (const float*)d_in[3];
    const float* encb    = (const float*)d_in[4];
    const float* nnW1    = (const float*)d_in[5];
    const float* nnb1    = (const float*)d_in[6];
    const float* nnW2    = (const float*)d_in[7];
    const float* nnb2    = (const float*)d_in[8];
    const float* mlpW    = (const float*)d_in[9];
    const float* mlpb    = (const float*)d_in[10];
    const float* bnG     = (const float*)d_in[11];
    const float* bnB     = (const float*)d_in[12];
    const float* fc1W    = (const float*)d_in[13];
    const float* fc1b    = (const float*)d_in[14];
    const float* fc2W    = (const float*)d_in[15];
    const float* fc2b    = (const float*)d_in[16];
    float* out = (float*)d_out;

    const int N = in_sizes[0] / 64;
    const int E = in_sizes[1] / 2;
    const int G = 512;
    const int* src = eidx;
    const int* dst = eidx + E;
    const int npb = (N + NBUCK - 1) / NBUCK;   // nodes per bucket (<=256)
    const float invN = 1.f / (float)N;
    const int CS = (((E + NBLK - 1) / NBLK) + 3) & ~3;   // multiple of 4 for int4 loads

    // workspace layout
    char* ws = (char*)d_ws;
    size_t off = 0;
    auto alloc = [&](size_t bytes) { size_t r = off; off = (off + bytes + 255) & ~(size_t)255; return r; };
    int*   rowptr  = (int*)(ws + alloc((size_t)(N + 1) * 4));
    int*   col     = (int*)(ws + alloc((size_t)E * 4));
    int2*  eDS     = (int2*)(ws + alloc((size_t)E * 8));
    int*   cnts    = (int*)(ws + alloc((size_t)NBLK * NBUCK * 4));
    int*   bases   = (int*)(ws + alloc((size_t)NBLK * NBUCK * 4));
    int*   btot    = (int*)(ws + alloc(NBUCK * 4));
    int*   bbase   = (int*)(ws + alloc(NBUCK * 4));
    float* cnt     = (float*)(ws + alloc((size_t)N * 4));
    unsigned short* baseF = (unsigned short*)(ws + alloc((size_t)N * 256 * 2 + 131072));  // +pad for OOB tile reads
    unsigned short* hC16 = (unsigned short*)(ws + alloc((size_t)N * 64 * 2 + 32768));     // +pad
    unsigned short* mWF  = (unsigned short*)(ws + alloc((size_t)5 * 64 * 768 * 2));
    unsigned short* nW1F = (unsigned short*)(ws + alloc((size_t)5 * 64 * 64 * 2));
    unsigned short* nW2F = (unsigned short*)(ws + alloc((size_t)5 * 64 * 64 * 2));
    float* bnstats = (float*)(ws + alloc(5 * 128 * 4));
    float* gpool   = (float*)(ws + alloc((size_t)G * 64 * 4));

    hipMemsetAsync(bnstats, 0, 5 * 128 * 4, stream);
    hipMemsetAsync(gpool, 0, (size_t)G * 64 * 4, stream);

    int ngrid64 = (N + 63) / 64;
    int ngrid128 = (N + 127) / 128;

    // CSR build: count -> scans -> scatter -> per-bucket CSR (no global atomics)
    k_cnt<<<NBLK, 512, 0, stream>>>(dst, cnts, E, npb, CS);
    k_bscan1<<<NBUCK, NBLK, 0, stream>>>(cnts, bases, btot);
    k_btops<<<1, NBUCK, 0, stream>>>(btot, bbase, rowptr, E, N);
    k_scat<<<NBLK, 512, 0, stream>>>(dst, src, bases, bbase, eDS, E, npb, CS);
    k_csr<<<NBUCK, 256, 0, stream>>>(eDS, bbase, btot, rowptr, col, cnt, npb, N);

    // cast weights to f16, MFMA-fragment-contiguous ([layer][sc][tile][lane][8])
    k_castw_mlp<<<120, 256, 0, stream>>>(mlpW, mWF, 30720);
    k_castw_nn<<<10, 256, 0, stream>>>(nnW1, nW1F, 2560);
    k_castw_nn<<<10, 256, 0, stream>>>(nnW2, nW2F, 2560);

    // encoder: hC16 = f16(x @ encW.T + encb)
    k_gemm64<<<ngrid64, 256, 0, stream>>>(x, encW, encb, hC16, N);

    for (int i = 0; i < 5; i++) {
        const float* bsPrev = (i == 0) ? bnstats : bnstats + (i - 1) * 128;
        const float* gP = (i == 0) ? bnG : bnG + (i - 1) * 64;
        const float* bP = (i == 0) ? bnB : bnB + (i - 1) * 64;
        int first = (i == 0) ? 1 : 0;
        k_agg<<<(N + 7) / 8, 256, 0, stream>>>(hC16, rowptr, col, bsPrev, gP, bP,
                                               invN, first, baseF, N);
        k_mlp<<<ngrid128, 256, 0, stream>>>(baseF, cnt,
                                            mWF + (size_t)i * 49152, mlpb + i * 64,
                                            hC16, bsPrev, gP, bP, invN, first,
                                            nW1F + (size_t)i * 4096, nnb1 + i * 64,
                                            nW2F + (size_t)i * 4096, nnb2 + i * 64,
                                            bnstats + i * 128, hC16, N);
    }

    k_pool<<<(N + 31) / 32, 256, 0, stream>>>(hC16, batch, bnstats + 4 * 128,
                                              bnG + 4 * 64, bnB + 4 * 64, invN, gpool, N);
    k_head<<<G, 64, 0, stream>>>(gpool, fc1W, fc1b, fc2W, fc2b, out);
}